// Round 2
// baseline (1165.442 us; speedup 1.0000x reference)
//
#include <hip/hip_runtime.h>
#include <stdint.h>

#define NB 64      // batch
#define NP 576     // patches
#define ND 768     // dim
#define NG 64      // groups
#define NN 65      // groups + 1 (cls)
#define NSTEPS 8
#define FLOORV 1.0e-4
#define EPSV   1.0e-4
#define DTV    0.1
#define GAMMAV 0.1
#define KEEPC  288  // max(1, round(576*0.5))

// ---------------------------------------------------------------- K1: group means
__global__ __launch_bounds__(256) void k_group_means(const float* __restrict__ tokens,
                                                     const float* __restrict__ cls,
                                                     float* __restrict__ nodes,
                                                     const int* __restrict__ ghp,
                                                     const int* __restrict__ gwp) {
    int bx = blockIdx.x;
    int b = bx / NN, n = bx - b * NN;
    int tid = threadIdx.x;
    float* orow = nodes + (size_t)bx * ND;
    if (n == 0) {
        for (int d = tid; d < ND; d += 256) orow[d] = cls[(size_t)b * ND + d];
        return;
    }
    int grid_h = *ghp, grid_w = *gwp;
    int gh = (grid_h + 7) / 8, gw = (grid_w + 7) / 8;
    int g = n - 1, gr = g >> 3, gc = g & 7;
    int r0 = gr * gh, r1 = (gr == 7) ? grid_h : min((gr + 1) * gh, grid_h);
    int c0 = gc * gw, c1 = (gc == 7) ? grid_w : min((gc + 1) * gw, grid_w);
    int cnt = (r1 > r0 && c1 > c0) ? (r1 - r0) * (c1 - c0) : 0;
    float cf = (float)max(cnt, 1);
    const float* tb = tokens + (size_t)b * NP * ND;
    for (int d = tid; d < ND; d += 256) {
        float acc = 0.f;
        for (int r = r0; r < r1; ++r)
            for (int c = c0; c < c1; ++c)
                acc += tb[(size_t)(r * grid_w + c) * ND + d];
        orow[d] = acc / cf;
    }
}

// ---------------------------------------------------------------- K2: proj = nodes @ W^T (NT gemm)
__global__ __launch_bounds__(256) void k_gemm_nt(const float* __restrict__ A,
                                                 const float* __restrict__ Bm,
                                                 float* __restrict__ Cm) {
    __shared__ float As[32][68];
    __shared__ float Bs[32][68];
    int tid = threadIdx.x;
    int m0 = blockIdx.x * 64, n0 = blockIdx.y * 64;
    int tx = tid & 15, ty = tid >> 4;
    float acc[4][4];
#pragma unroll
    for (int i = 0; i < 4; ++i)
#pragma unroll
        for (int j = 0; j < 4; ++j) acc[i][j] = 0.f;
    int lrow = tid >> 3, lq = tid & 7;
    for (int k0 = 0; k0 < ND; k0 += 32) {
#pragma unroll
        for (int l = 0; l < 2; ++l) {
            int row = lrow + l * 32;
            float4 va = *(const float4*)&A[(size_t)(m0 + row) * ND + k0 + lq * 4];
            As[lq * 4 + 0][row] = va.x; As[lq * 4 + 1][row] = va.y;
            As[lq * 4 + 2][row] = va.z; As[lq * 4 + 3][row] = va.w;
            float4 vb = *(const float4*)&Bm[(size_t)(n0 + row) * ND + k0 + lq * 4];
            Bs[lq * 4 + 0][row] = vb.x; Bs[lq * 4 + 1][row] = vb.y;
            Bs[lq * 4 + 2][row] = vb.z; Bs[lq * 4 + 3][row] = vb.w;
        }
        __syncthreads();
#pragma unroll
        for (int kk = 0; kk < 32; ++kk) {
            float4 a4 = *(const float4*)&As[kk][ty * 4];
            float4 b4 = *(const float4*)&Bs[kk][tx * 4];
            float av[4] = {a4.x, a4.y, a4.z, a4.w};
            float bv[4] = {b4.x, b4.y, b4.z, b4.w};
#pragma unroll
            for (int i = 0; i < 4; ++i)
#pragma unroll
                for (int j = 0; j < 4; ++j) acc[i][j] += av[i] * bv[j];
        }
        __syncthreads();
    }
#pragma unroll
    for (int i = 0; i < 4; ++i) {
        float4 o = make_float4(acc[i][0], acc[i][1], acc[i][2], acc[i][3]);
        *(float4*)&Cm[(size_t)(m0 + ty * 4 + i) * ND + n0 + tx * 4] = o;
    }
}

// ---------------------------------------------------------------- K3: row-normalize proj, sq = sum(projN^2)
__global__ __launch_bounds__(256) void k_normalize(float* __restrict__ proj, float* __restrict__ sqv) {
    int r = blockIdx.x, tid = threadIdx.x;
    __shared__ double red[8];
    __shared__ float invs;
    float* row = proj + (size_t)r * ND;
    double s = 0.0;
    for (int d = tid; d < ND; d += 256) { double v = (double)row[d]; s += v * v; }
#pragma unroll
    for (int off = 32; off; off >>= 1) s += __shfl_down(s, off, 64);
    int wid = tid >> 6, lane = tid & 63;
    if (lane == 0) red[wid] = s;
    __syncthreads();
    if (tid == 0) invs = (float)(1.0 / fmax(sqrt(red[0] + red[1] + red[2] + red[3]), 1e-12));
    __syncthreads();
    float inv = invs;
    double s2 = 0.0;
    for (int d = tid; d < ND; d += 256) {
        float v = row[d] * inv; row[d] = v; s2 += (double)v * (double)v;
    }
#pragma unroll
    for (int off = 32; off; off >>= 1) s2 += __shfl_down(s2, off, 64);
    __syncthreads();
    if (lane == 0) red[wid] = s2;
    __syncthreads();
    if (tid == 0) sqv[r] = (float)(red[0] + red[1] + red[2] + red[3]);
}

// ---------------------------------------------------------------- K4: C init = with_floor(exp(-d2)), write d_hist[:,0]
__global__ __launch_bounds__(256) void k_pairwise(const float* __restrict__ proj,
                                                  const float* __restrict__ sqv,
                                                  float* __restrict__ dhist) {
    int b = blockIdx.x, tid = threadIdx.x;
    int tx = tid & 15, ty = tid >> 4;
    __shared__ float Ps[NN][65];
    float acc[5][5];
#pragma unroll
    for (int a = 0; a < 5; ++a)
#pragma unroll
        for (int c = 0; c < 5; ++c) acc[a][c] = 0.f;
    const float* Pb = proj + (size_t)b * NN * ND;
    for (int k0 = 0; k0 < ND; k0 += 64) {
        __syncthreads();
        for (int idx = tid; idx < NN * 64; idx += 256) {
            int i = idx >> 6, kk = idx & 63;
            Ps[i][kk] = Pb[(size_t)i * ND + k0 + kk];
        }
        __syncthreads();
        for (int kk = 0; kk < 64; ++kk) {
            float av[5], bv[5];
#pragma unroll
            for (int a = 0; a < 5; ++a) { int i = ty + 16 * a; av[a] = (i < NN) ? Ps[i][kk] : 0.f; }
#pragma unroll
            for (int c = 0; c < 5; ++c) { int j = tx + 16 * c; bv[c] = (j < NN) ? Ps[j][kk] : 0.f; }
#pragma unroll
            for (int a = 0; a < 5; ++a)
#pragma unroll
                for (int c = 0; c < 5; ++c) acc[a][c] += av[a] * bv[c];
        }
    }
#pragma unroll
    for (int a = 0; a < 5; ++a)
#pragma unroll
        for (int c = 0; c < 5; ++c) {
            int i = ty + 16 * a, j = tx + 16 * c;
            if (i < NN && j < NN) {
                float d2 = fmaxf(sqv[b * NN + i] + sqv[b * NN + j] - 2.0f * acc[a][c], 0.f);
                double cv = exp(-(double)d2);   // TAU = 1
                float cf = (i == j) ? 0.f : fmaxf((float)cv, (float)FLOORV);
                dhist[(size_t)b * 9 * NN * NN + (size_t)i * NN + j] = cf;
            }
        }
}

// ---------------------------------------------------------------- K5: 8-step physarum dynamics
// ONE WAVE per batch. Lane L owns matrix row (L+1) in 66 fp64 registers; row 0 is
// only ever the first pivot (never updated) so it is recomputed from LDS when needed.
// Fully-unrolled Gaussian elimination: pivot-row broadcast via __shfl with
// compile-time lane index -> no barriers, no LDS in the solve, no scratch.
__global__ __launch_bounds__(64) void k_dynamics(float* __restrict__ dhist,
                                                 float* __restrict__ qhist,
                                                 double* __restrict__ part) {
    int b = blockIdx.x;
    int lane = threadIdx.x;          // 0..63
    __shared__ float Cs[NN * NN];    // current conductance, fp32 (16.9 KB)
    __shared__ double pd[NN];        // potentials
    float* C0 = dhist + (size_t)b * 9 * NN * NN;
    for (int t = lane; t < NN * NN; t += 64) Cs[t] = C0[t];
    __syncthreads();

    const int row_i = lane + 1;      // my matrix row (1..64)
    double stable = 0.0, sparse = 0.0;

    for (int step = 0; step < NSTEPS; ++step) {
        // ---- build my row: A[i][i] = deg_i + eps, A[i][j] = -C[i][j], rhs = -1/NG
        const float* crow = Cs + row_i * NN;
        double deg = 0.0;
        for (int j = 0; j < NN; ++j) deg += (double)crow[j];
        double row[NN + 1];
#pragma unroll
        for (int j = 0; j < NN; ++j)
            row[j] = (j == row_i) ? (deg + EPSV) : -(double)crow[j];
        row[NN] = -1.0 / NG;

        // deg0 (row 0 diagonal) — uniform across the wave
        double s0 = (double)Cs[lane];            // Cs[0][lane]
#pragma unroll
        for (int off = 32; off; off >>= 1) s0 += __shfl_down(s0, off, 64);
        s0 = __shfl(s0, 0, 64);
        double d0 = s0 + (double)Cs[64] + EPSV;  // + Cs[0][64]
        double invd0 = 1.0 / d0;

        // ---- elimination round k=0: pivot = virtual row 0 (A[0][j] = -C[0][j], rhs 1)
        {
            double f = row[0] * invd0;
#pragma unroll
            for (int j = 1; j < NN; ++j)
                row[j] += f * (double)Cs[j];     // row[j] -= f * (-C[0][j])
            row[NN] -= f;                        // rhs0 = 1.0
        }
        // ---- rounds k=1..63: pivot row k lives in lane k-1's registers
#pragma unroll
        for (int k = 1; k < NN - 1; ++k) {
            double dk = __shfl(row[k], k - 1, 64);
            double f = row[k] * (1.0 / dk);
            f = (lane >= k) ? f : 0.0;           // uniform control flow; masked by 0
#pragma unroll
            for (int j = k + 1; j <= NN; ++j) {
                double pv = __shfl(row[j], k - 1, 64);
                row[j] -= f * pv;
            }
        }

        // ---- back substitution (rows 64..1), then row 0
        double acc = 0.0, p_own = 0.0;
#pragma unroll
        for (int i = NN - 1; i >= 1; --i) {
            double diag = __shfl(row[i], i - 1, 64);
            double t = (row[NN] - acc) / diag;   // meaningful on lane i-1
            double pi = __shfl(t, i - 1, 64);
            if (lane == i - 1) p_own = t;
            acc += ((lane < i - 1) ? row[i] : 0.0) * pi;
        }
        // p0 = (1 + sum_j C[0][j] * p_j) / d0
        double sp0 = (double)Cs[lane + 1] * p_own;
#pragma unroll
        for (int off = 32; off; off >>= 1) sp0 += __shfl_down(sp0, off, 64);
        pd[lane + 1] = p_own;
        if (lane == 0) pd[0] = (1.0 + sp0) * invd0;
        __syncthreads();

        // ---- flow + conductance update (coalesced over 65x65)
        float* qout = qhist + ((size_t)b * NSTEPS + step) * NN * NN;
        float* dout = dhist + ((size_t)b * 9 + step + 1) * NN * NN;
        for (int t = lane; t < NN * NN; t += 64) {
            int i = t / NN, j = t - i * NN;
            float cf = Cs[t];
            double cij = (double)cf;
            double fl = cij * (pd[i] - pd[j]);
            qout[t] = (float)fl;
            double r = fabs(fl); r = r / (1.0 + r);
            double cn = cij + DTV * (r - GAMMAV * cij);
            float cnf = (i == j) ? 0.0f : (float)fmax(cn, FLOORV);
            Cs[t] = cnf;
            dout[t] = cnf;
            stable += fabs((double)cnf - cij);
            if (step == NSTEPS - 1 && i > 0 && j > 0) sparse += (double)cnf;
        }
        __syncthreads();
    }

#pragma unroll
    for (int off = 32; off; off >>= 1) {
        stable += __shfl_down(stable, off, 64);
        sparse += __shfl_down(sparse, off, 64);
    }
    if (lane == 0) {
        part[b]      = sparse;
        part[NB + b] = stable;
    }
}

// ---------------------------------------------------------------- K6: scores, top-k masks, gid, group_scores
__global__ __launch_bounds__(256) void k_scores(const float* __restrict__ qhist,
                                                const float* __restrict__ local,
                                                const int* __restrict__ ghp,
                                                const int* __restrict__ gwp,
                                                float* __restrict__ keep,
                                                float* __restrict__ patch,
                                                float* __restrict__ gidout,
                                                float* __restrict__ gsout) {
    int b = blockIdx.x, tid = threadIdx.x;
    __shared__ double gf[NG];
    __shared__ double ts[NP];
    __shared__ double red[8];
    __shared__ double stats[2];
    if (tid < NG) {
        const float* qrow = qhist + ((size_t)b * NSTEPS + (NSTEPS - 1)) * NN * NN + (size_t)(tid + 1) * NN;
        double s = 0.0;
        for (int j = 0; j < NN; ++j) s += fabs((double)qrow[j]);
        gf[tid] = s;
    }
    __syncthreads();
    if (tid < 64) {
        double v = gf[tid];
        double s = v;
#pragma unroll
        for (int off = 32; off; off >>= 1) s += __shfl_down(s, off, 64);
        double mean = __shfl(s, 0, 64) / (double)NG;
        double d = v - mean, ss = d * d;
#pragma unroll
        for (int off = 32; off; off >>= 1) ss += __shfl_down(ss, off, 64);
        if (tid == 0) { stats[0] = mean; stats[1] = 1.0 / fmax(sqrt(ss / (NG - 1)), 1e-6); }
    }
    const float* lrow = local + (size_t)b * NP;
    double s1 = 0.0;
    for (int p = tid; p < NP; p += 256) s1 += (double)lrow[p];
#pragma unroll
    for (int off = 32; off; off >>= 1) s1 += __shfl_down(s1, off, 64);
    int wid = tid >> 6, lane = tid & 63;
    if (lane == 0) red[wid] = s1;
    __syncthreads();
    double lmean = (red[0] + red[1] + red[2] + red[3]) / (double)NP;
    double s2 = 0.0;
    for (int p = tid; p < NP; p += 256) { double d = (double)lrow[p] - lmean; s2 += d * d; }
#pragma unroll
    for (int off = 32; off; off >>= 1) s2 += __shfl_down(s2, off, 64);
    __syncthreads();
    if (lane == 0) red[wid] = s2;
    __syncthreads();
    double linv = 1.0 / fmax(sqrt((red[0] + red[1] + red[2] + red[3]) / (double)(NP - 1)), 1e-6);
    double gmean = stats[0], ginv = stats[1];
    int grid_h = *ghp, grid_w = *gwp;
    int gh = (grid_h + 7) / 8, gw = (grid_w + 7) / 8;
    for (int p = tid; p < NP; p += 256) {
        int row = p / grid_w, col = p - row * grid_w;
        int g = min(row / gh, 7) * 8 + min(col / gw, 7);
        double gsc = (gf[g] - gmean) * ginv;
        double lsc = ((double)lrow[p] - lmean) * linv;
        ts[p] = gsc + 0.5 * lsc;  // FLOW_W=1, LOCAL_W=0.5
        gidout[(size_t)b * NP + p] = (float)g;
        gsout[(size_t)b * NP + p]  = (float)gsc;
    }
    __syncthreads();
    for (int p = tid; p < NP; p += 256) {
        double sp = ts[p];
        int c = 0;
        for (int q = 0; q < NP; ++q) {
            double v = ts[q];
            c += (v > sp) || (v == sp && q < p);
        }
        float kf = (c < KEEPC) ? 1.0f : 0.0f;
        patch[(size_t)b * NP + p] = kf;
        keep[(size_t)b * (NP + 1) + 1 + p] = kf;
    }
    if (tid == 0) keep[(size_t)b * (NP + 1)] = 1.0f;
}

// ---------------------------------------------------------------- K7: routing rows
__global__ void k_routing(const float* __restrict__ dhist, float* __restrict__ rout) {
    int b = blockIdx.x, tid = threadIdx.x;  // 64 threads
    const float* Crow = dhist + ((size_t)b * 9 + 8) * NN * NN + (size_t)(tid + 1) * NN + 1;
    double s = 0.0;
    for (int j = 0; j < NG; ++j) s += (double)Crow[j];
    double inv = 1.0 / fmax(s, 1e-6);
    float* orow = rout + ((size_t)b * NG + tid) * NG;
    for (int j = 0; j < NG; ++j) orow[j] = (float)((double)Crow[j] * inv);
}

// ---------------------------------------------------------------- K8: aux scalar reduction
__global__ void k_aux(const double* __restrict__ part, float* __restrict__ osp, float* __restrict__ ost) {
    int tid = threadIdx.x;  // 64 threads
    double sp = part[tid], st = part[NB + tid];
#pragma unroll
    for (int off = 32; off; off >>= 1) {
        sp += __shfl_down(sp, off, 64);
        st += __shfl_down(st, off, 64);
    }
    if (tid == 0) { *osp = (float)(sp / NB); *ost = (float)(st / NB); }
}

// ----------------------------------------------------------------
extern "C" void kernel_launch(void* const* d_in, const int* in_sizes, int n_in,
                              void* d_out, int out_size, void* d_ws, size_t ws_size,
                              hipStream_t stream) {
    const float* tokens = (const float*)d_in[0];
    const float* cls    = (const float*)d_in[1];
    const float* W      = (const float*)d_in[2];
    const float* local  = (const float*)d_in[3];
    const int* ghp = (const int*)d_in[4];
    const int* gwp = (const int*)d_in[5];

    float* out = (float*)d_out;
    float* o_keep  = out;                                   // NB x (NP+1)
    float* o_patch = o_keep + (size_t)NB * (NP + 1);        // NB x NP
    float* o_gid   = o_patch + (size_t)NB * NP;             // NB x NP
    float* o_gs    = o_gid + (size_t)NB * NP;               // NB x NP
    float* o_dh    = o_gs + (size_t)NB * NP;                // NB x 9 x NN x NN
    float* o_qh    = o_dh + (size_t)NB * 9 * NN * NN;       // NB x 8 x NN x NN
    float* o_rt    = o_qh + (size_t)NB * NSTEPS * NN * NN;  // NB x NG x NG
    float* o_sp    = o_rt + (size_t)NB * NG * NG;           // scalar
    float* o_st    = o_sp + 1;                              // scalar

    float* nodes = (float*)d_ws;                            // NB*NN x ND
    float* proj  = nodes + (size_t)NB * NN * ND;            // NB*NN x ND
    float* sqv   = proj + (size_t)NB * NN * ND;             // NB*NN
    double* part = (double*)(((uintptr_t)(sqv + NB * NN) + 15) & ~(uintptr_t)15);  // 2*NB

    k_group_means<<<NB * NN, 256, 0, stream>>>(tokens, cls, nodes, ghp, gwp);
    dim3 g2((NB * NN) / 64, ND / 64);
    k_gemm_nt<<<g2, 256, 0, stream>>>(nodes, W, proj);
    k_normalize<<<NB * NN, 256, 0, stream>>>(proj, sqv);
    k_pairwise<<<NB, 256, 0, stream>>>(proj, sqv, o_dh);
    k_dynamics<<<NB, 64, 0, stream>>>(o_dh, o_qh, part);
    k_scores<<<NB, 256, 0, stream>>>(o_qh, local, ghp, gwp, o_keep, o_patch, o_gid, o_gs);
    k_routing<<<NB, 64, 0, stream>>>(o_dh, o_rt);
    k_aux<<<1, 64, 0, stream>>>(part, o_sp, o_st);
}

// Round 4
// 968.754 us; speedup vs baseline: 1.2030x; 1.2030x over previous
//
#include <hip/hip_runtime.h>
#include <stdint.h>

#define NB 64      // batch
#define NP 576     // patches
#define ND 768     // dim
#define NG 64      // groups
#define NN 65      // groups + 1 (cls)
#define NSTEPS 8
#define FLOORV 1.0e-4
#define EPSV   1.0e-4
#define DTV    0.1
#define GAMMAV 0.1
#define KEEPC  288  // max(1, round(576*0.5))

// ---------------------------------------------------------------- K1: group means
__global__ __launch_bounds__(256) void k_group_means(const float* __restrict__ tokens,
                                                     const float* __restrict__ cls,
                                                     float* __restrict__ nodes,
                                                     const int* __restrict__ ghp,
                                                     const int* __restrict__ gwp) {
    int bx = blockIdx.x;
    int b = bx / NN, n = bx - b * NN;
    int tid = threadIdx.x;
    float* orow = nodes + (size_t)bx * ND;
    if (n == 0) {
        for (int d = tid; d < ND; d += 256) orow[d] = cls[(size_t)b * ND + d];
        return;
    }
    int grid_h = *ghp, grid_w = *gwp;
    int gh = (grid_h + 7) / 8, gw = (grid_w + 7) / 8;
    int g = n - 1, gr = g >> 3, gc = g & 7;
    int r0 = gr * gh, r1 = (gr == 7) ? grid_h : min((gr + 1) * gh, grid_h);
    int c0 = gc * gw, c1 = (gc == 7) ? grid_w : min((gc + 1) * gw, grid_w);
    int cnt = (r1 > r0 && c1 > c0) ? (r1 - r0) * (c1 - c0) : 0;
    float cf = (float)max(cnt, 1);
    const float* tb = tokens + (size_t)b * NP * ND;
    for (int d = tid; d < ND; d += 256) {
        float acc = 0.f;
        for (int r = r0; r < r1; ++r)
            for (int c = c0; c < c1; ++c)
                acc += tb[(size_t)(r * grid_w + c) * ND + d];
        orow[d] = acc / cf;
    }
}

// ---------------------------------------------------------------- K2: proj = nodes @ W^T (NT gemm)
__global__ __launch_bounds__(256) void k_gemm_nt(const float* __restrict__ A,
                                                 const float* __restrict__ Bm,
                                                 float* __restrict__ Cm) {
    __shared__ float As[32][68];
    __shared__ float Bs[32][68];
    int tid = threadIdx.x;
    int m0 = blockIdx.x * 64, n0 = blockIdx.y * 64;
    int tx = tid & 15, ty = tid >> 4;
    float acc[4][4];
#pragma unroll
    for (int i = 0; i < 4; ++i)
#pragma unroll
        for (int j = 0; j < 4; ++j) acc[i][j] = 0.f;
    int lrow = tid >> 3, lq = tid & 7;
    for (int k0 = 0; k0 < ND; k0 += 32) {
#pragma unroll
        for (int l = 0; l < 2; ++l) {
            int row = lrow + l * 32;
            float4 va = *(const float4*)&A[(size_t)(m0 + row) * ND + k0 + lq * 4];
            As[lq * 4 + 0][row] = va.x; As[lq * 4 + 1][row] = va.y;
            As[lq * 4 + 2][row] = va.z; As[lq * 4 + 3][row] = va.w;
            float4 vb = *(const float4*)&Bm[(size_t)(n0 + row) * ND + k0 + lq * 4];
            Bs[lq * 4 + 0][row] = vb.x; Bs[lq * 4 + 1][row] = vb.y;
            Bs[lq * 4 + 2][row] = vb.z; Bs[lq * 4 + 3][row] = vb.w;
        }
        __syncthreads();
#pragma unroll
        for (int kk = 0; kk < 32; ++kk) {
            float4 a4 = *(const float4*)&As[kk][ty * 4];
            float4 b4 = *(const float4*)&Bs[kk][tx * 4];
            float av[4] = {a4.x, a4.y, a4.z, a4.w};
            float bv[4] = {b4.x, b4.y, b4.z, b4.w};
#pragma unroll
            for (int i = 0; i < 4; ++i)
#pragma unroll
                for (int j = 0; j < 4; ++j) acc[i][j] += av[i] * bv[j];
        }
        __syncthreads();
    }
#pragma unroll
    for (int i = 0; i < 4; ++i) {
        float4 o = make_float4(acc[i][0], acc[i][1], acc[i][2], acc[i][3]);
        *(float4*)&Cm[(size_t)(m0 + ty * 4 + i) * ND + n0 + tx * 4] = o;
    }
}

// ---------------------------------------------------------------- K3: row-normalize proj, sq = sum(projN^2)
__global__ __launch_bounds__(256) void k_normalize(float* __restrict__ proj, float* __restrict__ sqv) {
    int r = blockIdx.x, tid = threadIdx.x;
    __shared__ double red[8];
    __shared__ float invs;
    float* row = proj + (size_t)r * ND;
    double s = 0.0;
    for (int d = tid; d < ND; d += 256) { double v = (double)row[d]; s += v * v; }
#pragma unroll
    for (int off = 32; off; off >>= 1) s += __shfl_down(s, off, 64);
    int wid = tid >> 6, lane = tid & 63;
    if (lane == 0) red[wid] = s;
    __syncthreads();
    if (tid == 0) invs = (float)(1.0 / fmax(sqrt(red[0] + red[1] + red[2] + red[3]), 1e-12));
    __syncthreads();
    float inv = invs;
    double s2 = 0.0;
    for (int d = tid; d < ND; d += 256) {
        float v = row[d] * inv; row[d] = v; s2 += (double)v * (double)v;
    }
#pragma unroll
    for (int off = 32; off; off >>= 1) s2 += __shfl_down(s2, off, 64);
    __syncthreads();
    if (lane == 0) red[wid] = s2;
    __syncthreads();
    if (tid == 0) sqv[r] = (float)(red[0] + red[1] + red[2] + red[3]);
}

// ---------------------------------------------------------------- K4: C init = with_floor(exp(-d2)), write d_hist[:,0]
__global__ __launch_bounds__(256) void k_pairwise(const float* __restrict__ proj,
                                                  const float* __restrict__ sqv,
                                                  float* __restrict__ dhist) {
    int b = blockIdx.x, tid = threadIdx.x;
    int tx = tid & 15, ty = tid >> 4;
    __shared__ float Ps[NN][65];
    float acc[5][5];
#pragma unroll
    for (int a = 0; a < 5; ++a)
#pragma unroll
        for (int c = 0; c < 5; ++c) acc[a][c] = 0.f;
    const float* Pb = proj + (size_t)b * NN * ND;
    for (int k0 = 0; k0 < ND; k0 += 64) {
        __syncthreads();
        for (int idx = tid; idx < NN * 64; idx += 256) {
            int i = idx >> 6, kk = idx & 63;
            Ps[i][kk] = Pb[(size_t)i * ND + k0 + kk];
        }
        __syncthreads();
        for (int kk = 0; kk < 64; ++kk) {
            float av[5], bv[5];
#pragma unroll
            for (int a = 0; a < 5; ++a) { int i = ty + 16 * a; av[a] = (i < NN) ? Ps[i][kk] : 0.f; }
#pragma unroll
            for (int c = 0; c < 5; ++c) { int j = tx + 16 * c; bv[c] = (j < NN) ? Ps[j][kk] : 0.f; }
#pragma unroll
            for (int a = 0; a < 5; ++a)
#pragma unroll
                for (int c = 0; c < 5; ++c) acc[a][c] += av[a] * bv[c];
        }
    }
#pragma unroll
    for (int a = 0; a < 5; ++a)
#pragma unroll
        for (int c = 0; c < 5; ++c) {
            int i = ty + 16 * a, j = tx + 16 * c;
            if (i < NN && j < NN) {
                float d2 = fmaxf(sqv[b * NN + i] + sqv[b * NN + j] - 2.0f * acc[a][c], 0.f);
                double cv = exp(-(double)d2);   // TAU = 1
                float cf = (i == j) ? 0.f : fmaxf((float)cv, (float)FLOORV);
                dhist[(size_t)b * 9 * NN * NN + (size_t)i * NN + j] = cf;
            }
        }
}

// ---------------------------------------------------------------- K5: 8-step physarum dynamics
// ONE WAVE per batch. Lane L owns matrix row (L+1) in 66 fp64 registers (static
// indices via full unroll). Pivot-row broadcast via LDS: owner lane writes its
// trailing row, __syncthreads() (cheap for 1 wave; defines the cross-lane
// ordering the R3 version raced on), then all lanes read it back with
// broadcast ds_read (conflict-free, bulk-issuable) — no per-element shuffles.
__global__ __launch_bounds__(64) void k_dynamics(float* __restrict__ dhist,
                                                 float* __restrict__ qhist,
                                                 double* __restrict__ part) {
    int b = blockIdx.x;
    int lane = threadIdx.x;          // 0..63
    __shared__ float Cs[NN * NN];    // current conductance, fp32 (16.9 KB)
    __shared__ double pd[NN];        // potentials
    __shared__ __align__(16) double prow[NN + 1];  // pivot-row broadcast buffer
    float* C0 = dhist + (size_t)b * 9 * NN * NN;
    for (int t = lane; t < NN * NN; t += 64) Cs[t] = C0[t];
    __syncthreads();

    const int row_i = lane + 1;      // my matrix row (1..64)
    double stable = 0.0, sparse = 0.0;

#pragma unroll 1
    for (int step = 0; step < NSTEPS; ++step) {
        // ---- build my row: A[i][i] = deg_i + eps, A[i][j] = -C[i][j], rhs = -1/NG
        const float* crow = Cs + row_i * NN;
        double deg = 0.0;
        for (int j = 0; j < NN; ++j) deg += (double)crow[j];
        double row[NN + 1];
#pragma unroll
        for (int j = 0; j < NN; ++j)
            row[j] = (j == row_i) ? (deg + EPSV) : -(double)crow[j];
        row[NN] = -1.0 / NG;

        // deg0 (row 0 diagonal) — uniform across the wave
        double s0 = (double)Cs[lane];            // Cs[0][lane]
#pragma unroll
        for (int off = 32; off; off >>= 1) s0 += __shfl_down(s0, off, 64);
        s0 = __shfl(s0, 0, 64);
        double d0 = s0 + (double)Cs[64] + EPSV;  // + Cs[0][64]
        double invd0 = 1.0 / d0;

        // ---- elimination round k=0: pivot = virtual row 0 (A[0][j] = -C[0][j], rhs 1)
        {
            double f = row[0] * invd0;
#pragma unroll
            for (int j = 1; j < NN; ++j)
                row[j] += f * (double)Cs[j];     // row[j] -= f * (-C[0][j])
            row[NN] -= f;                        // rhs0 = 1.0
        }
        // ---- rounds k=1..63: pivot row k lives in lane k-1's registers;
        //      broadcast it through LDS (sync!), then rank-1 update from registers.
#pragma unroll
        for (int k = 1; k < NN - 1; ++k) {
            if (lane == k - 1) {
#pragma unroll
                for (int j = k; j <= NN; ++j) prow[j] = row[j];
            }
            __syncthreads();                     // make owner's write visible
            double invdk = 1.0 / prow[k];
            double f = row[k] * invdk;
            f = (lane >= k) ? f : 0.0;           // uniform control flow; masked by 0
#pragma unroll
            for (int j = k + 1; j <= NN; ++j)
                row[j] -= f * prow[j];
            __syncthreads();                     // reads done before next owner write
        }

        // ---- back substitution (rows 64..1), then row 0
        double acc = 0.0, p_own = 0.0;
#pragma unroll
        for (int i = NN - 1; i >= 1; --i) {
            double diag = __shfl(row[i], i - 1, 64);
            double t = (row[NN] - acc) / diag;   // meaningful on lane i-1
            double pi = __shfl(t, i - 1, 64);
            if (lane == i - 1) p_own = t;
            acc += ((lane < i - 1) ? row[i] : 0.0) * pi;
        }
        // p0 = (1 + sum_j C[0][j] * p_j) / d0
        double sp0 = (double)Cs[lane + 1] * p_own;
#pragma unroll
        for (int off = 32; off; off >>= 1) sp0 += __shfl_down(sp0, off, 64);
        pd[lane + 1] = p_own;
        if (lane == 0) pd[0] = (1.0 + sp0) * invd0;
        __syncthreads();

        // ---- flow + conductance update (coalesced over 65x65)
        float* qout = qhist + ((size_t)b * NSTEPS + step) * NN * NN;
        float* dout = dhist + ((size_t)b * 9 + step + 1) * NN * NN;
        for (int t = lane; t < NN * NN; t += 64) {
            int i = t / NN, j = t - i * NN;
            float cf = Cs[t];
            double cij = (double)cf;
            double fl = cij * (pd[i] - pd[j]);
            qout[t] = (float)fl;
            double r = fabs(fl); r = r / (1.0 + r);
            double cn = cij + DTV * (r - GAMMAV * cij);
            float cnf = (i == j) ? 0.0f : (float)fmax(cn, FLOORV);
            Cs[t] = cnf;
            dout[t] = cnf;
            stable += fabs((double)cnf - cij);
            if (step == NSTEPS - 1 && i > 0 && j > 0) sparse += (double)cnf;
        }
        __syncthreads();
    }

#pragma unroll
    for (int off = 32; off; off >>= 1) {
        stable += __shfl_down(stable, off, 64);
        sparse += __shfl_down(sparse, off, 64);
    }
    if (lane == 0) {
        part[b]      = sparse;
        part[NB + b] = stable;
    }
}

// ---------------------------------------------------------------- K6: scores, top-k masks, gid, group_scores
__global__ __launch_bounds__(256) void k_scores(const float* __restrict__ qhist,
                                                const float* __restrict__ local,
                                                const int* __restrict__ ghp,
                                                const int* __restrict__ gwp,
                                                float* __restrict__ keep,
                                                float* __restrict__ patch,
                                                float* __restrict__ gidout,
                                                float* __restrict__ gsout) {
    int b = blockIdx.x, tid = threadIdx.x;
    __shared__ double gf[NG];
    __shared__ double ts[NP];
    __shared__ double red[8];
    __shared__ double stats[2];
    if (tid < NG) {
        const float* qrow = qhist + ((size_t)b * NSTEPS + (NSTEPS - 1)) * NN * NN + (size_t)(tid + 1) * NN;
        double s = 0.0;
        for (int j = 0; j < NN; ++j) s += fabs((double)qrow[j]);
        gf[tid] = s;
    }
    __syncthreads();
    if (tid < 64) {
        double v = gf[tid];
        double s = v;
#pragma unroll
        for (int off = 32; off; off >>= 1) s += __shfl_down(s, off, 64);
        double mean = __shfl(s, 0, 64) / (double)NG;
        double d = v - mean, ss = d * d;
#pragma unroll
        for (int off = 32; off; off >>= 1) ss += __shfl_down(ss, off, 64);
        if (tid == 0) { stats[0] = mean; stats[1] = 1.0 / fmax(sqrt(ss / (NG - 1)), 1e-6); }
    }
    const float* lrow = local + (size_t)b * NP;
    double s1 = 0.0;
    for (int p = tid; p < NP; p += 256) s1 += (double)lrow[p];
#pragma unroll
    for (int off = 32; off; off >>= 1) s1 += __shfl_down(s1, off, 64);
    int wid = tid >> 6, lane = tid & 63;
    if (lane == 0) red[wid] = s1;
    __syncthreads();
    double lmean = (red[0] + red[1] + red[2] + red[3]) / (double)NP;
    double s2 = 0.0;
    for (int p = tid; p < NP; p += 256) { double d = (double)lrow[p] - lmean; s2 += d * d; }
#pragma unroll
    for (int off = 32; off; off >>= 1) s2 += __shfl_down(s2, off, 64);
    __syncthreads();
    if (lane == 0) red[wid] = s2;
    __syncthreads();
    double linv = 1.0 / fmax(sqrt((red[0] + red[1] + red[2] + red[3]) / (double)(NP - 1)), 1e-6);
    double gmean = stats[0], ginv = stats[1];
    int grid_h = *ghp, grid_w = *gwp;
    int gh = (grid_h + 7) / 8, gw = (grid_w + 7) / 8;
    for (int p = tid; p < NP; p += 256) {
        int row = p / grid_w, col = p - row * grid_w;
        int g = min(row / gh, 7) * 8 + min(col / gw, 7);
        double gsc = (gf[g] - gmean) * ginv;
        double lsc = ((double)lrow[p] - lmean) * linv;
        ts[p] = gsc + 0.5 * lsc;  // FLOW_W=1, LOCAL_W=0.5
        gidout[(size_t)b * NP + p] = (float)g;
        gsout[(size_t)b * NP + p]  = (float)gsc;
    }
    __syncthreads();
    for (int p = tid; p < NP; p += 256) {
        double sp = ts[p];
        int c = 0;
        for (int q = 0; q < NP; ++q) {
            double v = ts[q];
            c += (v > sp) || (v == sp && q < p);
        }
        float kf = (c < KEEPC) ? 1.0f : 0.0f;
        patch[(size_t)b * NP + p] = kf;
        keep[(size_t)b * (NP + 1) + 1 + p] = kf;
    }
    if (tid == 0) keep[(size_t)b * (NP + 1)] = 1.0f;
}

// ---------------------------------------------------------------- K7: routing rows
__global__ void k_routing(const float* __restrict__ dhist, float* __restrict__ rout) {
    int b = blockIdx.x, tid = threadIdx.x;  // 64 threads
    const float* Crow = dhist + ((size_t)b * 9 + 8) * NN * NN + (size_t)(tid + 1) * NN + 1;
    double s = 0.0;
    for (int j = 0; j < NG; ++j) s += (double)Crow[j];
    double inv = 1.0 / fmax(s, 1e-6);
    float* orow = rout + ((size_t)b * NG + tid) * NG;
    for (int j = 0; j < NG; ++j) orow[j] = (float)((double)Crow[j] * inv);
}

// ---------------------------------------------------------------- K8: aux scalar reduction
__global__ void k_aux(const double* __restrict__ part, float* __restrict__ osp, float* __restrict__ ost) {
    int tid = threadIdx.x;  // 64 threads
    double sp = part[tid], st = part[NB + tid];
#pragma unroll
    for (int off = 32; off; off >>= 1) {
        sp += __shfl_down(sp, off, 64);
        st += __shfl_down(st, off, 64);
    }
    if (tid == 0) { *osp = (float)(sp / NB); *ost = (float)(st / NB); }
}

// ----------------------------------------------------------------
extern "C" void kernel_launch(void* const* d_in, const int* in_sizes, int n_in,
                              void* d_out, int out_size, void* d_ws, size_t ws_size,
                              hipStream_t stream) {
    const float* tokens = (const float*)d_in[0];
    const float* cls    = (const float*)d_in[1];
    const float* W      = (const float*)d_in[2];
    const float* local  = (const float*)d_in[3];
    const int* ghp = (const int*)d_in[4];
    const int* gwp = (const int*)d_in[5];

    float* out = (float*)d_out;
    float* o_keep  = out;                                   // NB x (NP+1)
    float* o_patch = o_keep + (size_t)NB * (NP + 1);        // NB x NP
    float* o_gid   = o_patch + (size_t)NB * NP;             // NB x NP
    float* o_gs    = o_gid + (size_t)NB * NP;               // NB x NP
    float* o_dh    = o_gs + (size_t)NB * NP;                // NB x 9 x NN x NN
    float* o_qh    = o_dh + (size_t)NB * 9 * NN * NN;       // NB x 8 x NN x NN
    float* o_rt    = o_qh + (size_t)NB * NSTEPS * NN * NN;  // NB x NG x NG
    float* o_sp    = o_rt + (size_t)NB * NG * NG;           // scalar
    float* o_st    = o_sp + 1;                              // scalar

    float* nodes = (float*)d_ws;                            // NB*NN x ND
    float* proj  = nodes + (size_t)NB * NN * ND;            // NB*NN x ND
    float* sqv   = proj + (size_t)NB * NN * ND;             // NB*NN
    double* part = (double*)(((uintptr_t)(sqv + NB * NN) + 15) & ~(uintptr_t)15);  // 2*NB

    k_group_means<<<NB * NN, 256, 0, stream>>>(tokens, cls, nodes, ghp, gwp);
    dim3 g2((NB * NN) / 64, ND / 64);
    k_gemm_nt<<<g2, 256, 0, stream>>>(nodes, W, proj);
    k_normalize<<<NB * NN, 256, 0, stream>>>(proj, sqv);
    k_pairwise<<<NB, 256, 0, stream>>>(proj, sqv, o_dh);
    k_dynamics<<<NB, 64, 0, stream>>>(o_dh, o_qh, part);
    k_scores<<<NB, 256, 0, stream>>>(o_qh, local, ghp, gwp, o_keep, o_patch, o_gid, o_gs);
    k_routing<<<NB, 64, 0, stream>>>(o_dh, o_rt);
    k_aux<<<1, 64, 0, stream>>>(part, o_sp, o_st);
}

// Round 5
// 843.098 us; speedup vs baseline: 1.3823x; 1.1490x over previous
//
#include <hip/hip_runtime.h>
#include <stdint.h>

#define NB 64      // batch
#define NP 576     // patches
#define ND 768     // dim
#define NG 64      // groups
#define NN 65      // groups + 1 (cls)
#define NSTEPS 8
#define FLOORV 1.0e-4f
#define EPSV   1.0e-4f
#define DTV    0.1f
#define GAMMAV 0.1f
#define KEEPC  288  // max(1, round(576*0.5))
#define PITCH  67   // Aug row pitch in floats (cols 0..64 = matrix, 65 = rhs, 66 = pad)

// ---------------------------------------------------------------- K1: group means
__global__ __launch_bounds__(256) void k_group_means(const float* __restrict__ tokens,
                                                     const float* __restrict__ cls,
                                                     float* __restrict__ nodes,
                                                     const int* __restrict__ ghp,
                                                     const int* __restrict__ gwp) {
    int bx = blockIdx.x;
    int b = bx / NN, n = bx - b * NN;
    int tid = threadIdx.x;
    float* orow = nodes + (size_t)bx * ND;
    if (n == 0) {
        for (int d = tid; d < ND; d += 256) orow[d] = cls[(size_t)b * ND + d];
        return;
    }
    int grid_h = *ghp, grid_w = *gwp;
    int gh = (grid_h + 7) / 8, gw = (grid_w + 7) / 8;
    int g = n - 1, gr = g >> 3, gc = g & 7;
    int r0 = gr * gh, r1 = (gr == 7) ? grid_h : min((gr + 1) * gh, grid_h);
    int c0 = gc * gw, c1 = (gc == 7) ? grid_w : min((gc + 1) * gw, grid_w);
    int cnt = (r1 > r0 && c1 > c0) ? (r1 - r0) * (c1 - c0) : 0;
    float cf = (float)max(cnt, 1);
    const float* tb = tokens + (size_t)b * NP * ND;
    for (int d = tid; d < ND; d += 256) {
        float acc = 0.f;
        for (int r = r0; r < r1; ++r)
            for (int c = c0; c < c1; ++c)
                acc += tb[(size_t)(r * grid_w + c) * ND + d];
        orow[d] = acc / cf;
    }
}

// ---------------------------------------------------------------- K2: proj = nodes @ W^T (NT gemm)
__global__ __launch_bounds__(256) void k_gemm_nt(const float* __restrict__ A,
                                                 const float* __restrict__ Bm,
                                                 float* __restrict__ Cm) {
    __shared__ float As[32][68];
    __shared__ float Bs[32][68];
    int tid = threadIdx.x;
    int m0 = blockIdx.x * 64, n0 = blockIdx.y * 64;
    int tx = tid & 15, ty = tid >> 4;
    float acc[4][4];
#pragma unroll
    for (int i = 0; i < 4; ++i)
#pragma unroll
        for (int j = 0; j < 4; ++j) acc[i][j] = 0.f;
    int lrow = tid >> 3, lq = tid & 7;
    for (int k0 = 0; k0 < ND; k0 += 32) {
#pragma unroll
        for (int l = 0; l < 2; ++l) {
            int row = lrow + l * 32;
            float4 va = *(const float4*)&A[(size_t)(m0 + row) * ND + k0 + lq * 4];
            As[lq * 4 + 0][row] = va.x; As[lq * 4 + 1][row] = va.y;
            As[lq * 4 + 2][row] = va.z; As[lq * 4 + 3][row] = va.w;
            float4 vb = *(const float4*)&Bm[(size_t)(n0 + row) * ND + k0 + lq * 4];
            Bs[lq * 4 + 0][row] = vb.x; Bs[lq * 4 + 1][row] = vb.y;
            Bs[lq * 4 + 2][row] = vb.z; Bs[lq * 4 + 3][row] = vb.w;
        }
        __syncthreads();
#pragma unroll
        for (int kk = 0; kk < 32; ++kk) {
            float4 a4 = *(const float4*)&As[kk][ty * 4];
            float4 b4 = *(const float4*)&Bs[kk][tx * 4];
            float av[4] = {a4.x, a4.y, a4.z, a4.w};
            float bv[4] = {b4.x, b4.y, b4.z, b4.w};
#pragma unroll
            for (int i = 0; i < 4; ++i)
#pragma unroll
                for (int j = 0; j < 4; ++j) acc[i][j] += av[i] * bv[j];
        }
        __syncthreads();
    }
#pragma unroll
    for (int i = 0; i < 4; ++i) {
        float4 o = make_float4(acc[i][0], acc[i][1], acc[i][2], acc[i][3]);
        *(float4*)&Cm[(size_t)(m0 + ty * 4 + i) * ND + n0 + tx * 4] = o;
    }
}

// ---------------------------------------------------------------- K3: row-normalize proj, sq = sum(projN^2)
__global__ __launch_bounds__(256) void k_normalize(float* __restrict__ proj, float* __restrict__ sqv) {
    int r = blockIdx.x, tid = threadIdx.x;
    __shared__ double red[8];
    __shared__ float invs;
    float* row = proj + (size_t)r * ND;
    double s = 0.0;
    for (int d = tid; d < ND; d += 256) { double v = (double)row[d]; s += v * v; }
#pragma unroll
    for (int off = 32; off; off >>= 1) s += __shfl_down(s, off, 64);
    int wid = tid >> 6, lane = tid & 63;
    if (lane == 0) red[wid] = s;
    __syncthreads();
    if (tid == 0) invs = (float)(1.0 / fmax(sqrt(red[0] + red[1] + red[2] + red[3]), 1e-12));
    __syncthreads();
    float inv = invs;
    double s2 = 0.0;
    for (int d = tid; d < ND; d += 256) {
        float v = row[d] * inv; row[d] = v; s2 += (double)v * (double)v;
    }
#pragma unroll
    for (int off = 32; off; off >>= 1) s2 += __shfl_down(s2, off, 64);
    __syncthreads();
    if (lane == 0) red[wid] = s2;
    __syncthreads();
    if (tid == 0) sqv[r] = (float)(red[0] + red[1] + red[2] + red[3]);
}

// ---------------------------------------------------------------- K4: C init = with_floor(exp(-d2)), write d_hist[:,0]
__global__ __launch_bounds__(256) void k_pairwise(const float* __restrict__ proj,
                                                  const float* __restrict__ sqv,
                                                  float* __restrict__ dhist) {
    int b = blockIdx.x, tid = threadIdx.x;
    int tx = tid & 15, ty = tid >> 4;
    __shared__ float Ps[NN][65];
    float acc[5][5];
#pragma unroll
    for (int a = 0; a < 5; ++a)
#pragma unroll
        for (int c = 0; c < 5; ++c) acc[a][c] = 0.f;
    const float* Pb = proj + (size_t)b * NN * ND;
    for (int k0 = 0; k0 < ND; k0 += 64) {
        __syncthreads();
        for (int idx = tid; idx < NN * 64; idx += 256) {
            int i = idx >> 6, kk = idx & 63;
            Ps[i][kk] = Pb[(size_t)i * ND + k0 + kk];
        }
        __syncthreads();
        for (int kk = 0; kk < 64; ++kk) {
            float av[5], bv[5];
#pragma unroll
            for (int a = 0; a < 5; ++a) { int i = ty + 16 * a; av[a] = (i < NN) ? Ps[i][kk] : 0.f; }
#pragma unroll
            for (int c = 0; c < 5; ++c) { int j = tx + 16 * c; bv[c] = (j < NN) ? Ps[j][kk] : 0.f; }
#pragma unroll
            for (int a = 0; a < 5; ++a)
#pragma unroll
                for (int c = 0; c < 5; ++c) acc[a][c] += av[a] * bv[c];
        }
    }
#pragma unroll
    for (int a = 0; a < 5; ++a)
#pragma unroll
        for (int c = 0; c < 5; ++c) {
            int i = ty + 16 * a, j = tx + 16 * c;
            if (i < NN && j < NN) {
                float d2 = fmaxf(sqv[b * NN + i] + sqv[b * NN + j] - 2.0f * acc[a][c], 0.f);
                double cv = exp(-(double)d2);   // TAU = 1
                float cf = (i == j) ? 0.f : fmaxf((float)cv, FLOORV);
                dhist[(size_t)b * 9 * NN * NN + (size_t)i * NN + j] = cf;
            }
        }
}

// ---------------------------------------------------------------- K5: 8-step physarum dynamics
// 256 threads per batch. Whole solve in fp32 (matches the jax reference's own
// precision). Augmented matrix in LDS (pitch 67 -> bank spread 3r+j), loops
// ROLLED (small code body; R2/R4's fully-unrolled versions were I-fetch bound).
// Elimination: 4 threads per row, one barrier per round; waves whose 16 rows
// are all <= k skip entirely. Back-substitution on wave 0 with precomputed
// per-lane 1/diag so the serial chain is shfl + prefetchable LDS read.
__global__ __launch_bounds__(256) void k_dynamics(float* __restrict__ dhist,
                                                  float* __restrict__ qhist,
                                                  double* __restrict__ part) {
    int b = blockIdx.x, tid = threadIdx.x;
    __shared__ float Cs[NN * NN];        // conductance, fp32 (16.9 KB)
    __shared__ float Aug[NN * PITCH];    // augmented system  (17.4 KB)
    __shared__ float pd[NN];             // potentials
    __shared__ double redd[8];
    float* C0 = dhist + (size_t)b * 9 * NN * NN;
    for (int t = tid; t < NN * NN; t += 256) Cs[t] = C0[t];
    __syncthreads();

    int r = tid >> 2, q = tid & 3;       // r in 0..63 -> matrix row r+1
    const int my_i = r + 1;
    double stable = 0.0, sparse = 0.0;

#pragma unroll 1
    for (int step = 0; step < NSTEPS; ++step) {
        // ---- build augmented system
        for (int t = tid; t < NN * NN; t += 256) {
            int i = t / NN, j = t - i * NN;
            if (i != j) Aug[i * PITCH + j] = -Cs[t];
        }
        if (tid < NN) {
            float s = 0.f;
            const float* cr = Cs + tid * NN;
#pragma unroll 1
            for (int j = 0; j < NN; ++j) s += cr[j];
            Aug[tid * PITCH + tid] = s + EPSV;
            Aug[tid * PITCH + NN] = (tid == 0) ? 1.0f : (-1.0f / NG);
        }
        __syncthreads();

        // ---- forward elimination (no pivoting; diagonally dominant)
#pragma unroll 1
        for (int k = 0; k < NN - 1; ++k) {
            if (my_i > k) {
                float invdk = 1.0f / Aug[k * PITCH + k];
                float f = Aug[my_i * PITCH + k] * invdk;
                const float* prow = Aug + k * PITCH;
                float* mrow = Aug + my_i * PITCH;
#pragma unroll 2
                for (int j = k + 1 + q; j <= NN; j += 4)
                    mrow[j] -= f * prow[j];
            }
            __syncthreads();
        }

        // ---- back substitution on wave 0 (lane L owns row L+1)
        if (tid < 64) {
            int lane = tid;
            int i_own = lane + 1;
            const float* mrow = Aug + i_own * PITCH;
            float inv_own = 1.0f / mrow[i_own];
            float rhs = mrow[NN];
            float acc = 0.f, p_own = 0.f;
#pragma unroll 2
            for (int i = NN - 1; i >= 1; --i) {
                float t = (rhs - acc) * inv_own;      // valid on lane i-1
                float pi = __shfl(t, i - 1, 64);
                if (i_own == i) p_own = t;
                acc += ((lane < i - 1) ? mrow[i] : 0.f) * pi;
                if (lane == 0) pd[i] = pi;
            }
            // p0 = (1 + sum_j C[0][j]*p_j) / d0   (row 0 never modified)
            float sp0 = Cs[i_own] * p_own;            // Cs[0][i_own]
#pragma unroll
            for (int off = 32; off; off >>= 1) sp0 += __shfl_down(sp0, off, 64);
            if (lane == 0) pd[0] = (1.0f + sp0) / Aug[0];
        }
        __syncthreads();

        // ---- flow + conductance update (fp32, matches reference)
        float* qout = qhist + ((size_t)b * NSTEPS + step) * NN * NN;
        float* dout = dhist + ((size_t)b * 9 + step + 1) * NN * NN;
        for (int t = tid; t < NN * NN; t += 256) {
            int i = t / NN, j = t - i * NN;
            float c = Cs[t];
            float fl = c * (pd[i] - pd[j]);
            qout[t] = fl;
            float rr = fabsf(fl); rr = rr / (1.0f + rr);
            float cn = c + DTV * (rr - GAMMAV * c);
            float cnf = (i == j) ? 0.0f : fmaxf(cn, FLOORV);
            Cs[t] = cnf;
            dout[t] = cnf;
            stable += fabs((double)cnf - (double)c);
            if (step == NSTEPS - 1 && i > 0 && j > 0) sparse += (double)cnf;
        }
        __syncthreads();
    }

#pragma unroll
    for (int off = 32; off; off >>= 1) {
        stable += __shfl_down(stable, off, 64);
        sparse += __shfl_down(sparse, off, 64);
    }
    int wid = tid >> 6, lane = tid & 63;
    if (lane == 0) { redd[wid] = stable; redd[4 + wid] = sparse; }
    __syncthreads();
    if (tid == 0) {
        part[b]      = redd[4] + redd[5] + redd[6] + redd[7];
        part[NB + b] = redd[0] + redd[1] + redd[2] + redd[3];
    }
}

// ---------------------------------------------------------------- K6: scores, top-k masks, gid, group_scores
__global__ __launch_bounds__(256) void k_scores(const float* __restrict__ qhist,
                                                const float* __restrict__ local,
                                                const int* __restrict__ ghp,
                                                const int* __restrict__ gwp,
                                                float* __restrict__ keep,
                                                float* __restrict__ patch,
                                                float* __restrict__ gidout,
                                                float* __restrict__ gsout) {
    int b = blockIdx.x, tid = threadIdx.x;
    __shared__ double gf[NG];
    __shared__ double ts[NP];
    __shared__ double red[8];
    __shared__ double stats[2];
    if (tid < NG) {
        const float* qrow = qhist + ((size_t)b * NSTEPS + (NSTEPS - 1)) * NN * NN + (size_t)(tid + 1) * NN;
        double s = 0.0;
        for (int j = 0; j < NN; ++j) s += fabs((double)qrow[j]);
        gf[tid] = s;
    }
    __syncthreads();
    if (tid < 64) {
        double v = gf[tid];
        double s = v;
#pragma unroll
        for (int off = 32; off; off >>= 1) s += __shfl_down(s, off, 64);
        double mean = __shfl(s, 0, 64) / (double)NG;
        double d = v - mean, ss = d * d;
#pragma unroll
        for (int off = 32; off; off >>= 1) ss += __shfl_down(ss, off, 64);
        if (tid == 0) { stats[0] = mean; stats[1] = 1.0 / fmax(sqrt(ss / (NG - 1)), 1e-6); }
    }
    const float* lrow = local + (size_t)b * NP;
    double s1 = 0.0;
    for (int p = tid; p < NP; p += 256) s1 += (double)lrow[p];
#pragma unroll
    for (int off = 32; off; off >>= 1) s1 += __shfl_down(s1, off, 64);
    int wid = tid >> 6, lane = tid & 63;
    if (lane == 0) red[wid] = s1;
    __syncthreads();
    double lmean = (red[0] + red[1] + red[2] + red[3]) / (double)NP;
    double s2 = 0.0;
    for (int p = tid; p < NP; p += 256) { double d = (double)lrow[p] - lmean; s2 += d * d; }
#pragma unroll
    for (int off = 32; off; off >>= 1) s2 += __shfl_down(s2, off, 64);
    __syncthreads();
    if (lane == 0) red[wid] = s2;
    __syncthreads();
    double linv = 1.0 / fmax(sqrt((red[0] + red[1] + red[2] + red[3]) / (double)(NP - 1)), 1e-6);
    double gmean = stats[0], ginv = stats[1];
    int grid_h = *ghp, grid_w = *gwp;
    int gh = (grid_h + 7) / 8, gw = (grid_w + 7) / 8;
    for (int p = tid; p < NP; p += 256) {
        int row = p / grid_w, col = p - row * grid_w;
        int g = min(row / gh, 7) * 8 + min(col / gw, 7);
        double gsc = (gf[g] - gmean) * ginv;
        double lsc = ((double)lrow[p] - lmean) * linv;
        ts[p] = gsc + 0.5 * lsc;  // FLOW_W=1, LOCAL_W=0.5
        gidout[(size_t)b * NP + p] = (float)g;
        gsout[(size_t)b * NP + p]  = (float)gsc;
    }
    __syncthreads();
    for (int p = tid; p < NP; p += 256) {
        double sp = ts[p];
        int c = 0;
        for (int qq = 0; qq < NP; ++qq) {
            double v = ts[qq];
            c += (v > sp) || (v == sp && qq < p);
        }
        float kf = (c < KEEPC) ? 1.0f : 0.0f;
        patch[(size_t)b * NP + p] = kf;
        keep[(size_t)b * (NP + 1) + 1 + p] = kf;
    }
    if (tid == 0) keep[(size_t)b * (NP + 1)] = 1.0f;
}

// ---------------------------------------------------------------- K7: routing rows
__global__ void k_routing(const float* __restrict__ dhist, float* __restrict__ rout) {
    int b = blockIdx.x, tid = threadIdx.x;  // 64 threads
    const float* Crow = dhist + ((size_t)b * 9 + 8) * NN * NN + (size_t)(tid + 1) * NN + 1;
    double s = 0.0;
    for (int j = 0; j < NG; ++j) s += (double)Crow[j];
    double inv = 1.0 / fmax(s, 1e-6);
    float* orow = rout + ((size_t)b * NG + tid) * NG;
    for (int j = 0; j < NG; ++j) orow[j] = (float)((double)Crow[j] * inv);
}

// ---------------------------------------------------------------- K8: aux scalar reduction
__global__ void k_aux(const double* __restrict__ part, float* __restrict__ osp, float* __restrict__ ost) {
    int tid = threadIdx.x;  // 64 threads
    double sp = part[tid], st = part[NB + tid];
#pragma unroll
    for (int off = 32; off; off >>= 1) {
        sp += __shfl_down(sp, off, 64);
        st += __shfl_down(st, off, 64);
    }
    if (tid == 0) { *osp = (float)(sp / NB); *ost = (float)(st / NB); }
}

// ----------------------------------------------------------------
extern "C" void kernel_launch(void* const* d_in, const int* in_sizes, int n_in,
                              void* d_out, int out_size, void* d_ws, size_t ws_size,
                              hipStream_t stream) {
    const float* tokens = (const float*)d_in[0];
    const float* cls    = (const float*)d_in[1];
    const float* W      = (const float*)d_in[2];
    const float* local  = (const float*)d_in[3];
    const int* ghp = (const int*)d_in[4];
    const int* gwp = (const int*)d_in[5];

    float* out = (float*)d_out;
    float* o_keep  = out;                                   // NB x (NP+1)
    float* o_patch = o_keep + (size_t)NB * (NP + 1);        // NB x NP
    float* o_gid   = o_patch + (size_t)NB * NP;             // NB x NP
    float* o_gs    = o_gid + (size_t)NB * NP;               // NB x NP
    float* o_dh    = o_gs + (size_t)NB * NP;                // NB x 9 x NN x NN
    float* o_qh    = o_dh + (size_t)NB * 9 * NN * NN;       // NB x 8 x NN x NN
    float* o_rt    = o_qh + (size_t)NB * NSTEPS * NN * NN;  // NB x NG x NG
    float* o_sp    = o_rt + (size_t)NB * NG * NG;           // scalar
    float* o_st    = o_sp + 1;                              // scalar

    float* nodes = (float*)d_ws;                            // NB*NN x ND
    float* proj  = nodes + (size_t)NB * NN * ND;            // NB*NN x ND
    float* sqv   = proj + (size_t)NB * NN * ND;             // NB*NN
    double* part = (double*)(((uintptr_t)(sqv + NB * NN) + 15) & ~(uintptr_t)15);  // 2*NB

    k_group_means<<<NB * NN, 256, 0, stream>>>(tokens, cls, nodes, ghp, gwp);
    dim3 g2((NB * NN) / 64, ND / 64);
    k_gemm_nt<<<g2, 256, 0, stream>>>(nodes, W, proj);
    k_normalize<<<NB * NN, 256, 0, stream>>>(proj, sqv);
    k_pairwise<<<NB, 256, 0, stream>>>(proj, sqv, o_dh);
    k_dynamics<<<NB, 256, 0, stream>>>(o_dh, o_qh, part);
    k_scores<<<NB, 256, 0, stream>>>(o_qh, local, ghp, gwp, o_keep, o_patch, o_gid, o_gs);
    k_routing<<<NB, 64, 0, stream>>>(o_dh, o_rt);
    k_aux<<<1, 64, 0, stream>>>(part, o_sp, o_st);
}

// Round 6
// 719.200 us; speedup vs baseline: 1.6205x; 1.1723x over previous
//
#include <hip/hip_runtime.h>
#include <stdint.h>

#define NB 64      // batch
#define NP 576     // patches
#define ND 768     // dim
#define NG 64      // groups
#define NN 65      // groups + 1 (cls)
#define NSTEPS 8
#define FLOORV 1.0e-4f
#define EPSV   1.0e-4f
#define DTV    0.1f
#define GAMMAV 0.1f
#define KEEPC  288  // max(1, round(576*0.5))
#define PITCH2 68   // Aug row pitch in floats: cols 0..64 matrix, 65 rhs, 66..67 pad

// ---------------------------------------------------------------- K1: group means
__global__ __launch_bounds__(256) void k_group_means(const float* __restrict__ tokens,
                                                     const float* __restrict__ cls,
                                                     float* __restrict__ nodes,
                                                     const int* __restrict__ ghp,
                                                     const int* __restrict__ gwp) {
    int bx = blockIdx.x;
    int b = bx / NN, n = bx - b * NN;
    int tid = threadIdx.x;
    float* orow = nodes + (size_t)bx * ND;
    if (n == 0) {
        for (int d = tid; d < ND; d += 256) orow[d] = cls[(size_t)b * ND + d];
        return;
    }
    int grid_h = *ghp, grid_w = *gwp;
    int gh = (grid_h + 7) / 8, gw = (grid_w + 7) / 8;
    int g = n - 1, gr = g >> 3, gc = g & 7;
    int r0 = gr * gh, r1 = (gr == 7) ? grid_h : min((gr + 1) * gh, grid_h);
    int c0 = gc * gw, c1 = (gc == 7) ? grid_w : min((gc + 1) * gw, grid_w);
    int cnt = (r1 > r0 && c1 > c0) ? (r1 - r0) * (c1 - c0) : 0;
    float cf = (float)max(cnt, 1);
    const float* tb = tokens + (size_t)b * NP * ND;
    for (int d = tid; d < ND; d += 256) {
        float acc = 0.f;
        for (int r = r0; r < r1; ++r)
            for (int c = c0; c < c1; ++c)
                acc += tb[(size_t)(r * grid_w + c) * ND + d];
        orow[d] = acc / cf;
    }
}

// ---------------------------------------------------------------- K2: proj = nodes @ W^T (NT gemm)
__global__ __launch_bounds__(256) void k_gemm_nt(const float* __restrict__ A,
                                                 const float* __restrict__ Bm,
                                                 float* __restrict__ Cm) {
    __shared__ float As[32][68];
    __shared__ float Bs[32][68];
    int tid = threadIdx.x;
    int m0 = blockIdx.x * 64, n0 = blockIdx.y * 64;
    int tx = tid & 15, ty = tid >> 4;
    float acc[4][4];
#pragma unroll
    for (int i = 0; i < 4; ++i)
#pragma unroll
        for (int j = 0; j < 4; ++j) acc[i][j] = 0.f;
    int lrow = tid >> 3, lq = tid & 7;
    for (int k0 = 0; k0 < ND; k0 += 32) {
#pragma unroll
        for (int l = 0; l < 2; ++l) {
            int row = lrow + l * 32;
            float4 va = *(const float4*)&A[(size_t)(m0 + row) * ND + k0 + lq * 4];
            As[lq * 4 + 0][row] = va.x; As[lq * 4 + 1][row] = va.y;
            As[lq * 4 + 2][row] = va.z; As[lq * 4 + 3][row] = va.w;
            float4 vb = *(const float4*)&Bm[(size_t)(n0 + row) * ND + k0 + lq * 4];
            Bs[lq * 4 + 0][row] = vb.x; Bs[lq * 4 + 1][row] = vb.y;
            Bs[lq * 4 + 2][row] = vb.z; Bs[lq * 4 + 3][row] = vb.w;
        }
        __syncthreads();
#pragma unroll
        for (int kk = 0; kk < 32; ++kk) {
            float4 a4 = *(const float4*)&As[kk][ty * 4];
            float4 b4 = *(const float4*)&Bs[kk][tx * 4];
            float av[4] = {a4.x, a4.y, a4.z, a4.w};
            float bv[4] = {b4.x, b4.y, b4.z, b4.w};
#pragma unroll
            for (int i = 0; i < 4; ++i)
#pragma unroll
                for (int j = 0; j < 4; ++j) acc[i][j] += av[i] * bv[j];
        }
        __syncthreads();
    }
#pragma unroll
    for (int i = 0; i < 4; ++i) {
        float4 o = make_float4(acc[i][0], acc[i][1], acc[i][2], acc[i][3]);
        *(float4*)&Cm[(size_t)(m0 + ty * 4 + i) * ND + n0 + tx * 4] = o;
    }
}

// ---------------------------------------------------------------- K3: row-normalize proj, sq = sum(projN^2)
__global__ __launch_bounds__(256) void k_normalize(float* __restrict__ proj, float* __restrict__ sqv) {
    int r = blockIdx.x, tid = threadIdx.x;
    __shared__ double red[8];
    __shared__ float invs;
    float* row = proj + (size_t)r * ND;
    double s = 0.0;
    for (int d = tid; d < ND; d += 256) { double v = (double)row[d]; s += v * v; }
#pragma unroll
    for (int off = 32; off; off >>= 1) s += __shfl_down(s, off, 64);
    int wid = tid >> 6, lane = tid & 63;
    if (lane == 0) red[wid] = s;
    __syncthreads();
    if (tid == 0) invs = (float)(1.0 / fmax(sqrt(red[0] + red[1] + red[2] + red[3]), 1e-12));
    __syncthreads();
    float inv = invs;
    double s2 = 0.0;
    for (int d = tid; d < ND; d += 256) {
        float v = row[d] * inv; row[d] = v; s2 += (double)v * (double)v;
    }
#pragma unroll
    for (int off = 32; off; off >>= 1) s2 += __shfl_down(s2, off, 64);
    __syncthreads();
    if (lane == 0) red[wid] = s2;
    __syncthreads();
    if (tid == 0) sqv[r] = (float)(red[0] + red[1] + red[2] + red[3]);
}

// ---------------------------------------------------------------- K4: C init = with_floor(exp(-d2)), write d_hist[:,0]
__global__ __launch_bounds__(256) void k_pairwise(const float* __restrict__ proj,
                                                  const float* __restrict__ sqv,
                                                  float* __restrict__ dhist) {
    int b = blockIdx.x, tid = threadIdx.x;
    int tx = tid & 15, ty = tid >> 4;
    __shared__ float Ps[NN][65];
    float acc[5][5];
#pragma unroll
    for (int a = 0; a < 5; ++a)
#pragma unroll
        for (int c = 0; c < 5; ++c) acc[a][c] = 0.f;
    const float* Pb = proj + (size_t)b * NN * ND;
    for (int k0 = 0; k0 < ND; k0 += 64) {
        __syncthreads();
        for (int idx = tid; idx < NN * 64; idx += 256) {
            int i = idx >> 6, kk = idx & 63;
            Ps[i][kk] = Pb[(size_t)i * ND + k0 + kk];
        }
        __syncthreads();
        for (int kk = 0; kk < 64; ++kk) {
            float av[5], bv[5];
#pragma unroll
            for (int a = 0; a < 5; ++a) { int i = ty + 16 * a; av[a] = (i < NN) ? Ps[i][kk] : 0.f; }
#pragma unroll
            for (int c = 0; c < 5; ++c) { int j = tx + 16 * c; bv[c] = (j < NN) ? Ps[j][kk] : 0.f; }
#pragma unroll
            for (int a = 0; a < 5; ++a)
#pragma unroll
                for (int c = 0; c < 5; ++c) acc[a][c] += av[a] * bv[c];
        }
    }
#pragma unroll
    for (int a = 0; a < 5; ++a)
#pragma unroll
        for (int c = 0; c < 5; ++c) {
            int i = ty + 16 * a, j = tx + 16 * c;
            if (i < NN && j < NN) {
                float d2 = fmaxf(sqv[b * NN + i] + sqv[b * NN + j] - 2.0f * acc[a][c], 0.f);
                double cv = exp(-(double)d2);   // TAU = 1
                float cf = (i == j) ? 0.f : fmaxf((float)cv, FLOORV);
                dhist[(size_t)b * 9 * NN * NN + (size_t)i * NN + j] = cf;
            }
        }
}

// ---------------------------------------------------------------- K5: 8-step physarum dynamics
// 256 threads per batch, fp32 solve (R5 numerics: absmax 0.004, threshold 10.12).
// COMPOUND TWO-PIVOT elimination: pair (k,k+1) applied as one rank-2 update
// A[i] -= c1*P + c2*Q computed entirely from pre-round values:
//   h = Q[k]/P[k]; Qd = Q[k+1]-h*P[k+1]; f = A[i][k]/P[k];
//   g = (A[i][k+1]-f*P[k+1])/Qd; c1 = f-g*h; c2 = g.
// -> 32 barriers/step instead of 64. Odd pivot rows (k+1) stay frozen during
// elimination (readers reconstruct Q' implicitly) and get one parallel fixup
// pass (row -= h*row_prev) before back-substitution.
// j-loop is constant full-width (subdiag of pivot rows are exact zeros by
// induction), fully unrolled -> all LDS reads issued in-flight per round.
__global__ __launch_bounds__(256) void k_dynamics(float* __restrict__ dhist,
                                                  float* __restrict__ qhist,
                                                  double* __restrict__ part) {
    int b = blockIdx.x, tid = threadIdx.x;
    __shared__ float Cs[NN * NN];         // conductance fp32 (16.9 KB)
    __shared__ float Aug[NN * PITCH2];    // augmented system (17.7 KB)
    __shared__ float pd[NN];              // potentials
    __shared__ double redd[8];
    float* C0 = dhist + (size_t)b * 9 * NN * NN;
    for (int t = tid; t < NN * NN; t += 256) Cs[t] = C0[t];
    __syncthreads();

    int r = tid >> 2, q = tid & 3;        // 4 threads per row; row = r+1 (1..64)
    const int my_i = r + 1;
    float* mrow = Aug + my_i * PITCH2;
    double stable = 0.0, sparse = 0.0;

#pragma unroll 1
    for (int step = 0; step < NSTEPS; ++step) {
        // ---- build augmented system (off-diag + pads; diag/rhs by tid<NN pass)
        for (int t = tid; t < NN * PITCH2; t += 256) {
            int i = t / PITCH2, j = t - i * PITCH2;
            if (j != i && j != NN)
                Aug[t] = (j < NN) ? -Cs[i * NN + j] : 0.f;
        }
        if (tid < NN) {
            float s = 0.f;
            const float* cr = Cs + tid * NN;
#pragma unroll 4
            for (int j = 0; j < NN; ++j) s += cr[j];
            Aug[tid * PITCH2 + tid] = s + EPSV;
            Aug[tid * PITCH2 + NN] = (tid == 0) ? 1.0f : (-1.0f / NG);
        }
        __syncthreads();

        // ---- compound two-pivot forward elimination: 32 rounds
#pragma unroll 1
        for (int k = 0; k < NN - 1; k += 2) {
            if (my_i > k + 1) {
                const float* P = Aug + k * PITCH2;
                const float* Q = P + PITCH2;
                float Pk = P[k], Pk1 = P[k + 1];
                float Qk = Q[k], Qk1 = Q[k + 1];
                float Aik = mrow[k], Aik1 = mrow[k + 1];
                float invP = 1.0f / Pk;
                float h = Qk * invP;
                float Qd = Qk1 - h * Pk1;
                float f = Aik * invP;
                float g = (Aik1 - f * Pk1) / Qd;
                float c1 = f - g * h, c2 = g;
                const float4* P4 = (const float4*)P;
                const float4* Q4 = (const float4*)Q;
                float4* M4 = (float4*)mrow;
#pragma unroll
                for (int u = 0; u < 4; ++u) {
                    int t = q + 4 * u;
                    float4 p = P4[t], qv = Q4[t], m = M4[t];
                    m.x -= c1 * p.x + c2 * qv.x;
                    m.y -= c1 * p.y + c2 * qv.y;
                    m.z -= c1 * p.z + c2 * qv.z;
                    m.w -= c1 * p.w + c2 * qv.w;
                    M4[t] = m;
                }
                if (q == 0) {
                    float4 p = P4[16], qv = Q4[16], m = M4[16];
                    m.x -= c1 * p.x + c2 * qv.x;
                    m.y -= c1 * p.y + c2 * qv.y;
                    m.z -= c1 * p.z + c2 * qv.z;
                    m.w -= c1 * p.w + c2 * qv.w;
                    M4[16] = m;
                }
            }
            __syncthreads();
        }

        // ---- fixup frozen odd pivot rows: row i -= h * row (i-1), i = 1,3,..,63
        {
            int fr = 2 * (tid >> 3) + 1;     // 32 rows x 8 threads
            int l8 = tid & 7;
            float* R = Aug + fr * PITCH2;
            const float* Pp = R - PITCH2;
            float h = R[fr - 1] / Pp[fr - 1];
            float4* R4 = (float4*)R;
            const float4* Pp4 = (const float4*)Pp;
#pragma unroll
            for (int u = 0; u < 2; ++u) {
                int t = l8 + 8 * u;
                float4 a = R4[t], p = Pp4[t];
                a.x -= h * p.x; a.y -= h * p.y; a.z -= h * p.z; a.w -= h * p.w;
                R4[t] = a;
            }
            if (l8 == 0) {
                float4 a = R4[16], p = Pp4[16];
                a.x -= h * p.x; a.y -= h * p.y; a.z -= h * p.z; a.w -= h * p.w;
                R4[16] = a;
            }
        }
        __syncthreads();

        // ---- back substitution on wave 0 (lane L owns row L+1)
        if (tid < 64) {
            int lane = tid;
            int i_own = lane + 1;
            const float* brow = Aug + i_own * PITCH2;
            float inv_own = 1.0f / brow[i_own];
            float rhs = brow[NN];
            float acc = 0.f, p_own = 0.f;
#pragma unroll 2
            for (int i = NN - 1; i >= 1; --i) {
                float t = (rhs - acc) * inv_own;      // valid on lane i-1
                float pi = __shfl(t, i - 1, 64);
                if (i_own == i) p_own = t;
                acc += ((lane < i - 1) ? brow[i] : 0.f) * pi;
                if (lane == 0) pd[i] = pi;
            }
            // p0 = (1 + sum_j C[0][j]*p_j) / d0   (row 0 never modified)
            float sp0 = Cs[i_own] * p_own;            // Cs[0][i_own]
#pragma unroll
            for (int off = 32; off; off >>= 1) sp0 += __shfl_down(sp0, off, 64);
            if (lane == 0) pd[0] = (1.0f + sp0) / Aug[0];
        }
        __syncthreads();

        // ---- flow + conductance update (fp32, matches reference)
        float* qout = qhist + ((size_t)b * NSTEPS + step) * NN * NN;
        float* dout = dhist + ((size_t)b * 9 + step + 1) * NN * NN;
        for (int t = tid; t < NN * NN; t += 256) {
            int i = t / NN, j = t - i * NN;
            float c = Cs[t];
            float fl = c * (pd[i] - pd[j]);
            qout[t] = fl;
            float rr = fabsf(fl); rr = rr / (1.0f + rr);
            float cn = c + DTV * (rr - GAMMAV * c);
            float cnf = (i == j) ? 0.0f : fmaxf(cn, FLOORV);
            Cs[t] = cnf;
            dout[t] = cnf;
            stable += fabs((double)cnf - (double)c);
            if (step == NSTEPS - 1 && i > 0 && j > 0) sparse += (double)cnf;
        }
        __syncthreads();
    }

#pragma unroll
    for (int off = 32; off; off >>= 1) {
        stable += __shfl_down(stable, off, 64);
        sparse += __shfl_down(sparse, off, 64);
    }
    int wid = tid >> 6, lane = tid & 63;
    if (lane == 0) { redd[wid] = stable; redd[4 + wid] = sparse; }
    __syncthreads();
    if (tid == 0) {
        part[b]      = redd[4] + redd[5] + redd[6] + redd[7];
        part[NB + b] = redd[0] + redd[1] + redd[2] + redd[3];
    }
}

// ---------------------------------------------------------------- K6: scores, top-k masks, gid, group_scores
__global__ __launch_bounds__(256) void k_scores(const float* __restrict__ qhist,
                                                const float* __restrict__ local,
                                                const int* __restrict__ ghp,
                                                const int* __restrict__ gwp,
                                                float* __restrict__ keep,
                                                float* __restrict__ patch,
                                                float* __restrict__ gidout,
                                                float* __restrict__ gsout) {
    int b = blockIdx.x, tid = threadIdx.x;
    __shared__ double gf[NG];
    __shared__ double ts[NP];
    __shared__ double red[8];
    __shared__ double stats[2];
    if (tid < NG) {
        const float* qrow = qhist + ((size_t)b * NSTEPS + (NSTEPS - 1)) * NN * NN + (size_t)(tid + 1) * NN;
        double s = 0.0;
        for (int j = 0; j < NN; ++j) s += fabs((double)qrow[j]);
        gf[tid] = s;
    }
    __syncthreads();
    if (tid < 64) {
        double v = gf[tid];
        double s = v;
#pragma unroll
        for (int off = 32; off; off >>= 1) s += __shfl_down(s, off, 64);
        double mean = __shfl(s, 0, 64) / (double)NG;
        double d = v - mean, ss = d * d;
#pragma unroll
        for (int off = 32; off; off >>= 1) ss += __shfl_down(ss, off, 64);
        if (tid == 0) { stats[0] = mean; stats[1] = 1.0 / fmax(sqrt(ss / (NG - 1)), 1e-6); }
    }
    const float* lrow = local + (size_t)b * NP;
    double s1 = 0.0;
    for (int p = tid; p < NP; p += 256) s1 += (double)lrow[p];
#pragma unroll
    for (int off = 32; off; off >>= 1) s1 += __shfl_down(s1, off, 64);
    int wid = tid >> 6, lane = tid & 63;
    if (lane == 0) red[wid] = s1;
    __syncthreads();
    double lmean = (red[0] + red[1] + red[2] + red[3]) / (double)NP;
    double s2 = 0.0;
    for (int p = tid; p < NP; p += 256) { double d = (double)lrow[p] - lmean; s2 += d * d; }
#pragma unroll
    for (int off = 32; off; off >>= 1) s2 += __shfl_down(s2, off, 64);
    __syncthreads();
    if (lane == 0) red[wid] = s2;
    __syncthreads();
    double linv = 1.0 / fmax(sqrt((red[0] + red[1] + red[2] + red[3]) / (double)(NP - 1)), 1e-6);
    double gmean = stats[0], ginv = stats[1];
    int grid_h = *ghp, grid_w = *gwp;
    int gh = (grid_h + 7) / 8, gw = (grid_w + 7) / 8;
    for (int p = tid; p < NP; p += 256) {
        int row = p / grid_w, col = p - row * grid_w;
        int g = min(row / gh, 7) * 8 + min(col / gw, 7);
        double gsc = (gf[g] - gmean) * ginv;
        double lsc = ((double)lrow[p] - lmean) * linv;
        ts[p] = gsc + 0.5 * lsc;  // FLOW_W=1, LOCAL_W=0.5
        gidout[(size_t)b * NP + p] = (float)g;
        gsout[(size_t)b * NP + p]  = (float)gsc;
    }
    __syncthreads();
    for (int p = tid; p < NP; p += 256) {
        double sp = ts[p];
        int c = 0;
        for (int qq = 0; qq < NP; ++qq) {
            double v = ts[qq];
            c += (v > sp) || (v == sp && qq < p);
        }
        float kf = (c < KEEPC) ? 1.0f : 0.0f;
        patch[(size_t)b * NP + p] = kf;
        keep[(size_t)b * (NP + 1) + 1 + p] = kf;
    }
    if (tid == 0) keep[(size_t)b * (NP + 1)] = 1.0f;
}

// ---------------------------------------------------------------- K7: routing rows
__global__ void k_routing(const float* __restrict__ dhist, float* __restrict__ rout) {
    int b = blockIdx.x, tid = threadIdx.x;  // 64 threads
    const float* Crow = dhist + ((size_t)b * 9 + 8) * NN * NN + (size_t)(tid + 1) * NN + 1;
    double s = 0.0;
    for (int j = 0; j < NG; ++j) s += (double)Crow[j];
    double inv = 1.0 / fmax(s, 1e-6);
    float* orow = rout + ((size_t)b * NG + tid) * NG;
    for (int j = 0; j < NG; ++j) orow[j] = (float)((double)Crow[j] * inv);
}

// ---------------------------------------------------------------- K8: aux scalar reduction
__global__ void k_aux(const double* __restrict__ part, float* __restrict__ osp, float* __restrict__ ost) {
    int tid = threadIdx.x;  // 64 threads
    double sp = part[tid], st = part[NB + tid];
#pragma unroll
    for (int off = 32; off; off >>= 1) {
        sp += __shfl_down(sp, off, 64);
        st += __shfl_down(st, off, 64);
    }
    if (tid == 0) { *osp = (float)(sp / NB); *ost = (float)(st / NB); }
}

// ----------------------------------------------------------------
extern "C" void kernel_launch(void* const* d_in, const int* in_sizes, int n_in,
                              void* d_out, int out_size, void* d_ws, size_t ws_size,
                              hipStream_t stream) {
    const float* tokens = (const float*)d_in[0];
    const float* cls    = (const float*)d_in[1];
    const float* W      = (const float*)d_in[2];
    const float* local  = (const float*)d_in[3];
    const int* ghp = (const int*)d_in[4];
    const int* gwp = (const int*)d_in[5];

    float* out = (float*)d_out;
    float* o_keep  = out;                                   // NB x (NP+1)
    float* o_patch = o_keep + (size_t)NB * (NP + 1);        // NB x NP
    float* o_gid   = o_patch + (size_t)NB * NP;             // NB x NP
    float* o_gs    = o_gid + (size_t)NB * NP;               // NB x NP
    float* o_dh    = o_gs + (size_t)NB * NP;                // NB x 9 x NN x NN
    float* o_qh    = o_dh + (size_t)NB * 9 * NN * NN;       // NB x 8 x NN x NN
    float* o_rt    = o_qh + (size_t)NB * NSTEPS * NN * NN;  // NB x NG x NG
    float* o_sp    = o_rt + (size_t)NB * NG * NG;           // scalar
    float* o_st    = o_sp + 1;                              // scalar

    float* nodes = (float*)d_ws;                            // NB*NN x ND
    float* proj  = nodes + (size_t)NB * NN * ND;            // NB*NN x ND
    float* sqv   = proj + (size_t)NB * NN * ND;             // NB*NN
    double* part = (double*)(((uintptr_t)(sqv + NB * NN) + 15) & ~(uintptr_t)15);  // 2*NB

    k_group_means<<<NB * NN, 256, 0, stream>>>(tokens, cls, nodes, ghp, gwp);
    dim3 g2((NB * NN) / 64, ND / 64);
    k_gemm_nt<<<g2, 256, 0, stream>>>(nodes, W, proj);
    k_normalize<<<NB * NN, 256, 0, stream>>>(proj, sqv);
    k_pairwise<<<NB, 256, 0, stream>>>(proj, sqv, o_dh);
    k_dynamics<<<NB, 256, 0, stream>>>(o_dh, o_qh, part);
    k_scores<<<NB, 256, 0, stream>>>(o_qh, local, ghp, gwp, o_keep, o_patch, o_gid, o_gs);
    k_routing<<<NB, 64, 0, stream>>>(o_dh, o_rt);
    k_aux<<<1, 64, 0, stream>>>(part, o_sp, o_st);
}

// Round 7
// 684.958 us; speedup vs baseline: 1.7015x; 1.0500x over previous
//
#include <hip/hip_runtime.h>
#include <stdint.h>

#define NB 64      // batch
#define NP 576     // patches
#define ND 768     // dim
#define NG 64      // groups
#define NN 65      // groups + 1 (cls)
#define NSTEPS 8
#define FLOORV 1.0e-4f
#define EPSV   1.0e-4f
#define DTV    0.1f
#define GAMMAV 0.1f
#define KEEPC  288  // max(1, round(576*0.5))
#define PITCH2 68   // Aug row pitch in floats: cols 0..64 matrix, 65 rhs, 66..67 pad

// ---------------------------------------------------------------- K1: group means
__global__ __launch_bounds__(256) void k_group_means(const float* __restrict__ tokens,
                                                     const float* __restrict__ cls,
                                                     float* __restrict__ nodes,
                                                     const int* __restrict__ ghp,
                                                     const int* __restrict__ gwp) {
    int bx = blockIdx.x;
    int b = bx / NN, n = bx - b * NN;
    int tid = threadIdx.x;
    float* orow = nodes + (size_t)bx * ND;
    if (n == 0) {
        for (int d = tid; d < ND; d += 256) orow[d] = cls[(size_t)b * ND + d];
        return;
    }
    int grid_h = *ghp, grid_w = *gwp;
    int gh = (grid_h + 7) / 8, gw = (grid_w + 7) / 8;
    int g = n - 1, gr = g >> 3, gc = g & 7;
    int r0 = gr * gh, r1 = (gr == 7) ? grid_h : min((gr + 1) * gh, grid_h);
    int c0 = gc * gw, c1 = (gc == 7) ? grid_w : min((gc + 1) * gw, grid_w);
    int cnt = (r1 > r0 && c1 > c0) ? (r1 - r0) * (c1 - c0) : 0;
    float cf = (float)max(cnt, 1);
    const float* tb = tokens + (size_t)b * NP * ND;
    for (int d = tid; d < ND; d += 256) {
        float acc = 0.f;
        for (int r = r0; r < r1; ++r)
            for (int c = c0; c < c1; ++c)
                acc += tb[(size_t)(r * grid_w + c) * ND + d];
        orow[d] = acc / cf;
    }
}

// ---------------------------------------------------------------- K2: proj = nodes @ W^T (NT gemm)
__global__ __launch_bounds__(256) void k_gemm_nt(const float* __restrict__ A,
                                                 const float* __restrict__ Bm,
                                                 float* __restrict__ Cm) {
    __shared__ float As[32][68];
    __shared__ float Bs[32][68];
    int tid = threadIdx.x;
    int m0 = blockIdx.x * 64, n0 = blockIdx.y * 64;
    int tx = tid & 15, ty = tid >> 4;
    float acc[4][4];
#pragma unroll
    for (int i = 0; i < 4; ++i)
#pragma unroll
        for (int j = 0; j < 4; ++j) acc[i][j] = 0.f;
    int lrow = tid >> 3, lq = tid & 7;
    for (int k0 = 0; k0 < ND; k0 += 32) {
#pragma unroll
        for (int l = 0; l < 2; ++l) {
            int row = lrow + l * 32;
            float4 va = *(const float4*)&A[(size_t)(m0 + row) * ND + k0 + lq * 4];
            As[lq * 4 + 0][row] = va.x; As[lq * 4 + 1][row] = va.y;
            As[lq * 4 + 2][row] = va.z; As[lq * 4 + 3][row] = va.w;
            float4 vb = *(const float4*)&Bm[(size_t)(n0 + row) * ND + k0 + lq * 4];
            Bs[lq * 4 + 0][row] = vb.x; Bs[lq * 4 + 1][row] = vb.y;
            Bs[lq * 4 + 2][row] = vb.z; Bs[lq * 4 + 3][row] = vb.w;
        }
        __syncthreads();
#pragma unroll
        for (int kk = 0; kk < 32; ++kk) {
            float4 a4 = *(const float4*)&As[kk][ty * 4];
            float4 b4 = *(const float4*)&Bs[kk][tx * 4];
            float av[4] = {a4.x, a4.y, a4.z, a4.w};
            float bv[4] = {b4.x, b4.y, b4.z, b4.w};
#pragma unroll
            for (int i = 0; i < 4; ++i)
#pragma unroll
                for (int j = 0; j < 4; ++j) acc[i][j] += av[i] * bv[j];
        }
        __syncthreads();
    }
#pragma unroll
    for (int i = 0; i < 4; ++i) {
        float4 o = make_float4(acc[i][0], acc[i][1], acc[i][2], acc[i][3]);
        *(float4*)&Cm[(size_t)(m0 + ty * 4 + i) * ND + n0 + tx * 4] = o;
    }
}

// ---------------------------------------------------------------- K3: row-normalize proj, sq = sum(projN^2)
__global__ __launch_bounds__(256) void k_normalize(float* __restrict__ proj, float* __restrict__ sqv) {
    int r = blockIdx.x, tid = threadIdx.x;
    __shared__ double red[8];
    __shared__ float invs;
    float* row = proj + (size_t)r * ND;
    double s = 0.0;
    for (int d = tid; d < ND; d += 256) { double v = (double)row[d]; s += v * v; }
#pragma unroll
    for (int off = 32; off; off >>= 1) s += __shfl_down(s, off, 64);
    int wid = tid >> 6, lane = tid & 63;
    if (lane == 0) red[wid] = s;
    __syncthreads();
    if (tid == 0) invs = (float)(1.0 / fmax(sqrt(red[0] + red[1] + red[2] + red[3]), 1e-12));
    __syncthreads();
    float inv = invs;
    double s2 = 0.0;
    for (int d = tid; d < ND; d += 256) {
        float v = row[d] * inv; row[d] = v; s2 += (double)v * (double)v;
    }
#pragma unroll
    for (int off = 32; off; off >>= 1) s2 += __shfl_down(s2, off, 64);
    __syncthreads();
    if (lane == 0) red[wid] = s2;
    __syncthreads();
    if (tid == 0) sqv[r] = (float)(red[0] + red[1] + red[2] + red[3]);
}

// ---------------------------------------------------------------- K4: C init = with_floor(exp(-d2)), write d_hist[:,0]
__global__ __launch_bounds__(256) void k_pairwise(const float* __restrict__ proj,
                                                  const float* __restrict__ sqv,
                                                  float* __restrict__ dhist) {
    int b = blockIdx.x, tid = threadIdx.x;
    int tx = tid & 15, ty = tid >> 4;
    __shared__ float Ps[NN][65];
    float acc[5][5];
#pragma unroll
    for (int a = 0; a < 5; ++a)
#pragma unroll
        for (int c = 0; c < 5; ++c) acc[a][c] = 0.f;
    const float* Pb = proj + (size_t)b * NN * ND;
    for (int k0 = 0; k0 < ND; k0 += 64) {
        __syncthreads();
        for (int idx = tid; idx < NN * 64; idx += 256) {
            int i = idx >> 6, kk = idx & 63;
            Ps[i][kk] = Pb[(size_t)i * ND + k0 + kk];
        }
        __syncthreads();
        for (int kk = 0; kk < 64; ++kk) {
            float av[5], bv[5];
#pragma unroll
            for (int a = 0; a < 5; ++a) { int i = ty + 16 * a; av[a] = (i < NN) ? Ps[i][kk] : 0.f; }
#pragma unroll
            for (int c = 0; c < 5; ++c) { int j = tx + 16 * c; bv[c] = (j < NN) ? Ps[j][kk] : 0.f; }
#pragma unroll
            for (int a = 0; a < 5; ++a)
#pragma unroll
                for (int c = 0; c < 5; ++c) acc[a][c] += av[a] * bv[c];
        }
    }
#pragma unroll
    for (int a = 0; a < 5; ++a)
#pragma unroll
        for (int c = 0; c < 5; ++c) {
            int i = ty + 16 * a, j = tx + 16 * c;
            if (i < NN && j < NN) {
                float d2 = fmaxf(sqv[b * NN + i] + sqv[b * NN + j] - 2.0f * acc[a][c], 0.f);
                double cv = exp(-(double)d2);   // TAU = 1
                float cf = (i == j) ? 0.f : fmaxf((float)cv, FLOORV);
                dhist[(size_t)b * 9 * NN * NN + (size_t)i * NN + j] = cf;
            }
        }
}

// ---------------------------------------------------------------- K5: 8-step physarum dynamics
// 256 threads per batch, fp32 solve. RANK-4 block elimination: 16 rounds/step.
// For pivot block k..k+3, the 4x4 block N (N[c][a] = P_a[k+c], stale pivot rows)
// is wave-uniform; every thread redundantly computes Ninv = N^-1 (Gauss-Jordan,
// no pivoting -- diag-dominant M-matrix principal block). Each row i >= k+4:
// x = Ninv * A[i][k..k+3] (one aligned b128 read), then rank-4 update
// A[i][:] -= sum_a x_a * P_a[:]  (pivot reads are 4-address broadcasts).
// Identical to 4 sequential GE rounds (unique quotient in the pivot-row span).
// Frozen pivot rows k+1..k+3 get a 3-substep intra-block triangularization
// after all rounds (16 groups x 16 threads, __syncthreads between substeps).
__global__ __launch_bounds__(256) void k_dynamics(float* __restrict__ dhist,
                                                  float* __restrict__ qhist,
                                                  double* __restrict__ part) {
    int b = blockIdx.x, tid = threadIdx.x;
    __shared__ float Cs[NN * NN];         // conductance fp32 (16.9 KB)
    __shared__ float Aug[NN * PITCH2];    // augmented system (17.7 KB)
    __shared__ float pd[NN];              // potentials
    __shared__ double redd[8];
    float* C0 = dhist + (size_t)b * 9 * NN * NN;
    for (int t = tid; t < NN * NN; t += 256) Cs[t] = C0[t];
    __syncthreads();

    int r = tid >> 2, q = tid & 3;        // 4 threads per row; row = r+1 (1..64)
    const int my_i = r + 1;
    float* mrow = Aug + my_i * PITCH2;
    double stable = 0.0, sparse = 0.0;

#pragma unroll 1
    for (int step = 0; step < NSTEPS; ++step) {
        // ---- build augmented system
        for (int t = tid; t < NN * PITCH2; t += 256) {
            int i = t / PITCH2, j = t - i * PITCH2;
            if (j != i && j != NN)
                Aug[t] = (j < NN) ? -Cs[i * NN + j] : 0.f;
        }
        if (tid < NN) {
            float s = 0.f;
            const float* cr = Cs + tid * NN;
#pragma unroll 4
            for (int j = 0; j < NN; ++j) s += cr[j];
            Aug[tid * PITCH2 + tid] = s + EPSV;
            Aug[tid * PITCH2 + NN] = (tid == 0) ? 1.0f : (-1.0f / NG);
        }
        __syncthreads();

        // ---- rank-4 forward elimination: 16 rounds
#pragma unroll 1
        for (int k = 0; k < NN - 1; k += 4) {
            // uniform: N[c][a] = Aug[(k+a)][k+c]  (solve N x = avec)
            float N4[4][4], Iv[4][4];
#pragma unroll
            for (int a = 0; a < 4; ++a)
#pragma unroll
                for (int c = 0; c < 4; ++c) {
                    N4[c][a] = Aug[(k + a) * PITCH2 + k + c];
                    Iv[c][a] = (a == c) ? 1.0f : 0.0f;
                }
            // Gauss-Jordan inversion (no pivoting)
#pragma unroll
            for (int p = 0; p < 4; ++p) {
                float ip = 1.0f / N4[p][p];
#pragma unroll
                for (int c = 0; c < 4; ++c) { N4[p][c] *= ip; Iv[p][c] *= ip; }
#pragma unroll
                for (int rr = 0; rr < 4; ++rr) {
                    if (rr != p) {
                        float f = N4[rr][p];
#pragma unroll
                        for (int c = 0; c < 4; ++c) {
                            N4[rr][c] -= f * N4[p][c];
                            Iv[rr][c] -= f * Iv[p][c];
                        }
                    }
                }
            }
            if (my_i >= k + 4) {
                float4 av = *(const float4*)(mrow + k);
                float x0 = Iv[0][0]*av.x + Iv[0][1]*av.y + Iv[0][2]*av.z + Iv[0][3]*av.w;
                float x1 = Iv[1][0]*av.x + Iv[1][1]*av.y + Iv[1][2]*av.z + Iv[1][3]*av.w;
                float x2 = Iv[2][0]*av.x + Iv[2][1]*av.y + Iv[2][2]*av.z + Iv[2][3]*av.w;
                float x3 = Iv[3][0]*av.x + Iv[3][1]*av.y + Iv[3][2]*av.z + Iv[3][3]*av.w;
                const float4* P0 = (const float4*)(Aug + (k + 0) * PITCH2);
                const float4* P1 = (const float4*)(Aug + (k + 1) * PITCH2);
                const float4* P2 = (const float4*)(Aug + (k + 2) * PITCH2);
                const float4* P3 = (const float4*)(Aug + (k + 3) * PITCH2);
                float4* M4 = (float4*)mrow;
#pragma unroll
                for (int u = 0; u < 5; ++u) {
                    int t = q + 4 * u;
                    if (t < 17) {
                        float4 m = M4[t];
                        float4 p0 = P0[t], p1 = P1[t], p2 = P2[t], p3 = P3[t];
                        m.x -= x0 * p0.x + x1 * p1.x + x2 * p2.x + x3 * p3.x;
                        m.y -= x0 * p0.y + x1 * p1.y + x2 * p2.y + x3 * p3.y;
                        m.z -= x0 * p0.z + x1 * p1.z + x2 * p2.z + x3 * p3.z;
                        m.w -= x0 * p0.w + x1 * p1.w + x2 * p2.w + x3 * p3.w;
                        M4[t] = m;
                    }
                }
            }
            __syncthreads();
        }

        // ---- fixup frozen pivot rows: intra-block triangularization
        {
            int g = tid >> 4, l16 = tid & 15;
            int base = g << 2;
            float* R0 = Aug + base * PITCH2;
            float* R1 = R0 + PITCH2;
            float* R2 = R1 + PITCH2;
            float* R3 = R2 + PITCH2;
            float4* R1v = (float4*)R1; float4* R2v = (float4*)R2; float4* R3v = (float4*)R3;
            const float4* R0v = (const float4*)R0;
            float inv0 = 1.0f / R0[base];
            // substep 1: R1 -= l10 * R0
            float l10 = R1[base] * inv0;
            { float4 a = R1v[l16], p = R0v[l16];
              a.x -= l10*p.x; a.y -= l10*p.y; a.z -= l10*p.z; a.w -= l10*p.w; R1v[l16] = a; }
            if (l16 == 0) { float4 a = R1v[16], p = R0v[16];
              a.x -= l10*p.x; a.y -= l10*p.y; a.z -= l10*p.z; a.w -= l10*p.w; R1v[16] = a; }
            __syncthreads();
            // substep 2: R2 -= l20*R0 + l21*R1'
            float l20 = R2[base] * inv0;
            float l21 = (R2[base+1] - l20 * R0[base+1]) / R1[base+1];
            { float4 a = R2v[l16], p = R0v[l16], t1 = R1v[l16];
              a.x -= l20*p.x + l21*t1.x; a.y -= l20*p.y + l21*t1.y;
              a.z -= l20*p.z + l21*t1.z; a.w -= l20*p.w + l21*t1.w; R2v[l16] = a; }
            if (l16 == 0) { float4 a = R2v[16], p = R0v[16], t1 = R1v[16];
              a.x -= l20*p.x + l21*t1.x; a.y -= l20*p.y + l21*t1.y;
              a.z -= l20*p.z + l21*t1.z; a.w -= l20*p.w + l21*t1.w; R2v[16] = a; }
            __syncthreads();
            // substep 3: R3 -= l30*R0 + l31*R1' + l32*R2'
            float l30 = R3[base] * inv0;
            float l31 = (R3[base+1] - l30 * R0[base+1]) / R1[base+1];
            float l32 = (R3[base+2] - l30 * R0[base+2] - l31 * R1[base+2]) / R2[base+2];
            { float4 a = R3v[l16], p = R0v[l16], t1 = R1v[l16], t2 = R2v[l16];
              a.x -= l30*p.x + l31*t1.x + l32*t2.x; a.y -= l30*p.y + l31*t1.y + l32*t2.y;
              a.z -= l30*p.z + l31*t1.z + l32*t2.z; a.w -= l30*p.w + l31*t1.w + l32*t2.w; R3v[l16] = a; }
            if (l16 == 0) { float4 a = R3v[16], p = R0v[16], t1 = R1v[16], t2 = R2v[16];
              a.x -= l30*p.x + l31*t1.x + l32*t2.x; a.y -= l30*p.y + l31*t1.y + l32*t2.y;
              a.z -= l30*p.z + l31*t1.z + l32*t2.z; a.w -= l30*p.w + l31*t1.w + l32*t2.w; R3v[16] = a; }
        }
        __syncthreads();

        // ---- back substitution on wave 0 (lane L owns row L+1)
        if (tid < 64) {
            int lane = tid;
            int i_own = lane + 1;
            const float* brow = Aug + i_own * PITCH2;
            float inv_own = 1.0f / brow[i_own];
            float rhs = brow[NN];
            float acc = 0.f, p_own = 0.f;
#pragma unroll 2
            for (int i = NN - 1; i >= 1; --i) {
                float t = (rhs - acc) * inv_own;      // valid on lane i-1
                float pi = __shfl(t, i - 1, 64);
                if (i_own == i) p_own = t;
                acc += ((lane < i - 1) ? brow[i] : 0.f) * pi;
                if (lane == 0) pd[i] = pi;
            }
            // p0 = (1 + sum_j C[0][j]*p_j) / d0   (row 0 never modified)
            float sp0 = Cs[i_own] * p_own;            // Cs[0][i_own]
#pragma unroll
            for (int off = 32; off; off >>= 1) sp0 += __shfl_down(sp0, off, 64);
            if (lane == 0) pd[0] = (1.0f + sp0) / Aug[0];
        }
        __syncthreads();

        // ---- flow + conductance update (fp32, matches reference)
        float* qout = qhist + ((size_t)b * NSTEPS + step) * NN * NN;
        float* dout = dhist + ((size_t)b * 9 + step + 1) * NN * NN;
        for (int t = tid; t < NN * NN; t += 256) {
            int i = t / NN, j = t - i * NN;
            float c = Cs[t];
            float fl = c * (pd[i] - pd[j]);
            qout[t] = fl;
            float rr = fabsf(fl); rr = rr / (1.0f + rr);
            float cn = c + DTV * (rr - GAMMAV * c);
            float cnf = (i == j) ? 0.0f : fmaxf(cn, FLOORV);
            Cs[t] = cnf;
            dout[t] = cnf;
            stable += fabs((double)cnf - (double)c);
            if (step == NSTEPS - 1 && i > 0 && j > 0) sparse += (double)cnf;
        }
        __syncthreads();
    }

#pragma unroll
    for (int off = 32; off; off >>= 1) {
        stable += __shfl_down(stable, off, 64);
        sparse += __shfl_down(sparse, off, 64);
    }
    int wid = tid >> 6, lane = tid & 63;
    if (lane == 0) { redd[wid] = stable; redd[4 + wid] = sparse; }
    __syncthreads();
    if (tid == 0) {
        part[b]      = redd[4] + redd[5] + redd[6] + redd[7];
        part[NB + b] = redd[0] + redd[1] + redd[2] + redd[3];
    }
}

// ---------------------------------------------------------------- K6: scores, top-k masks, gid, group_scores
__global__ __launch_bounds__(256) void k_scores(const float* __restrict__ qhist,
                                                const float* __restrict__ local,
                                                const int* __restrict__ ghp,
                                                const int* __restrict__ gwp,
                                                float* __restrict__ keep,
                                                float* __restrict__ patch,
                                                float* __restrict__ gidout,
                                                float* __restrict__ gsout) {
    int b = blockIdx.x, tid = threadIdx.x;
    __shared__ double gf[NG];
    __shared__ double ts[NP];
    __shared__ double red[8];
    __shared__ double stats[2];
    if (tid < NG) {
        const float* qrow = qhist + ((size_t)b * NSTEPS + (NSTEPS - 1)) * NN * NN + (size_t)(tid + 1) * NN;
        double s = 0.0;
        for (int j = 0; j < NN; ++j) s += fabs((double)qrow[j]);
        gf[tid] = s;
    }
    __syncthreads();
    if (tid < 64) {
        double v = gf[tid];
        double s = v;
#pragma unroll
        for (int off = 32; off; off >>= 1) s += __shfl_down(s, off, 64);
        double mean = __shfl(s, 0, 64) / (double)NG;
        double d = v - mean, ss = d * d;
#pragma unroll
        for (int off = 32; off; off >>= 1) ss += __shfl_down(ss, off, 64);
        if (tid == 0) { stats[0] = mean; stats[1] = 1.0 / fmax(sqrt(ss / (NG - 1)), 1e-6); }
    }
    const float* lrow = local + (size_t)b * NP;
    double s1 = 0.0;
    for (int p = tid; p < NP; p += 256) s1 += (double)lrow[p];
#pragma unroll
    for (int off = 32; off; off >>= 1) s1 += __shfl_down(s1, off, 64);
    int wid = tid >> 6, lane = tid & 63;
    if (lane == 0) red[wid] = s1;
    __syncthreads();
    double lmean = (red[0] + red[1] + red[2] + red[3]) / (double)NP;
    double s2 = 0.0;
    for (int p = tid; p < NP; p += 256) { double d = (double)lrow[p] - lmean; s2 += d * d; }
#pragma unroll
    for (int off = 32; off; off >>= 1) s2 += __shfl_down(s2, off, 64);
    __syncthreads();
    if (lane == 0) red[wid] = s2;
    __syncthreads();
    double linv = 1.0 / fmax(sqrt((red[0] + red[1] + red[2] + red[3]) / (double)(NP - 1)), 1e-6);
    double gmean = stats[0], ginv = stats[1];
    int grid_h = *ghp, grid_w = *gwp;
    int gh = (grid_h + 7) / 8, gw = (grid_w + 7) / 8;
    for (int p = tid; p < NP; p += 256) {
        int row = p / grid_w, col = p - row * grid_w;
        int g = min(row / gh, 7) * 8 + min(col / gw, 7);
        double gsc = (gf[g] - gmean) * ginv;
        double lsc = ((double)lrow[p] - lmean) * linv;
        ts[p] = gsc + 0.5 * lsc;  // FLOW_W=1, LOCAL_W=0.5
        gidout[(size_t)b * NP + p] = (float)g;
        gsout[(size_t)b * NP + p]  = (float)gsc;
    }
    __syncthreads();
    for (int p = tid; p < NP; p += 256) {
        double sp = ts[p];
        int c = 0;
        for (int qq = 0; qq < NP; ++qq) {
            double v = ts[qq];
            c += (v > sp) || (v == sp && qq < p);
        }
        float kf = (c < KEEPC) ? 1.0f : 0.0f;
        patch[(size_t)b * NP + p] = kf;
        keep[(size_t)b * (NP + 1) + 1 + p] = kf;
    }
    if (tid == 0) keep[(size_t)b * (NP + 1)] = 1.0f;
}

// ---------------------------------------------------------------- K7: routing rows
__global__ void k_routing(const float* __restrict__ dhist, float* __restrict__ rout) {
    int b = blockIdx.x, tid = threadIdx.x;  // 64 threads
    const float* Crow = dhist + ((size_t)b * 9 + 8) * NN * NN + (size_t)(tid + 1) * NN + 1;
    double s = 0.0;
    for (int j = 0; j < NG; ++j) s += (double)Crow[j];
    double inv = 1.0 / fmax(s, 1e-6);
    float* orow = rout + ((size_t)b * NG + tid) * NG;
    for (int j = 0; j < NG; ++j) orow[j] = (float)((double)Crow[j] * inv);
}

// ---------------------------------------------------------------- K8: aux scalar reduction
__global__ void k_aux(const double* __restrict__ part, float* __restrict__ osp, float* __restrict__ ost) {
    int tid = threadIdx.x;  // 64 threads
    double sp = part[tid], st = part[NB + tid];
#pragma unroll
    for (int off = 32; off; off >>= 1) {
        sp += __shfl_down(sp, off, 64);
        st += __shfl_down(st, off, 64);
    }
    if (tid == 0) { *osp = (float)(sp / NB); *ost = (float)(st / NB); }
}

// ----------------------------------------------------------------
extern "C" void kernel_launch(void* const* d_in, const int* in_sizes, int n_in,
                              void* d_out, int out_size, void* d_ws, size_t ws_size,
                              hipStream_t stream) {
    const float* tokens = (const float*)d_in[0];
    const float* cls    = (const float*)d_in[1];
    const float* W      = (const float*)d_in[2];
    const float* local  = (const float*)d_in[3];
    const int* ghp = (const int*)d_in[4];
    const int* gwp = (const int*)d_in[5];

    float* out = (float*)d_out;
    float* o_keep  = out;                                   // NB x (NP+1)
    float* o_patch = o_keep + (size_t)NB * (NP + 1);        // NB x NP
    float* o_gid   = o_patch + (size_t)NB * NP;             // NB x NP
    float* o_gs    = o_gid + (size_t)NB * NP;               // NB x NP
    float* o_dh    = o_gs + (size_t)NB * NP;                // NB x 9 x NN x NN
    float* o_qh    = o_dh + (size_t)NB * 9 * NN * NN;       // NB x 8 x NN x NN
    float* o_rt    = o_qh + (size_t)NB * NSTEPS * NN * NN;  // NB x NG x NG
    float* o_sp    = o_rt + (size_t)NB * NG * NG;           // scalar
    float* o_st    = o_sp + 1;                              // scalar

    float* nodes = (float*)d_ws;                            // NB*NN x ND
    float* proj  = nodes + (size_t)NB * NN * ND;            // NB*NN x ND
    float* sqv   = proj + (size_t)NB * NN * ND;             // NB*NN
    double* part = (double*)(((uintptr_t)(sqv + NB * NN) + 15) & ~(uintptr_t)15);  // 2*NB

    k_group_means<<<NB * NN, 256, 0, stream>>>(tokens, cls, nodes, ghp, gwp);
    dim3 g2((NB * NN) / 64, ND / 64);
    k_gemm_nt<<<g2, 256, 0, stream>>>(nodes, W, proj);
    k_normalize<<<NB * NN, 256, 0, stream>>>(proj, sqv);
    k_pairwise<<<NB, 256, 0, stream>>>(proj, sqv, o_dh);
    k_dynamics<<<NB, 256, 0, stream>>>(o_dh, o_qh, part);
    k_scores<<<NB, 256, 0, stream>>>(o_qh, local, ghp, gwp, o_keep, o_patch, o_gid, o_gs);
    k_routing<<<NB, 64, 0, stream>>>(o_dh, o_rt);
    k_aux<<<1, 64, 0, stream>>>(part, o_sp, o_st);
}